// Round 4
// baseline (375.999 us; speedup 1.0000x reference)
//
#include <hip/hip_runtime.h>
#include <math.h>

// Problem constants (LocallyEnhancedAttention: B=16, N=3136, C=256, SR=7, HEADS=8)
#define B_     16
#define H_IMG  56
#define W_IMG  56
#define N_TOK  3136      // 56*56
#define C_     256
#define C4_    64        // C_/4
#define NHEAD  8
#define HDIM   32
#define NCH    8         // attn pixel chunks (each = 7 image rows = 392 pixels)

typedef float f32x4 __attribute__((ext_vector_type(4)));
typedef __bf16 bf16x8 __attribute__((ext_vector_type(8)));

__device__ __forceinline__ float geluf(float x) {
    // jax.nn.gelu(approximate=False) = x * 0.5 * (1 + erf(x/sqrt(2)))
    return 0.5f * x * (1.0f + erff(x * 0.70710678118654752f));
}

// 8 -> 56 bilinear (half-pixel + edge renormalize == index clamp).
// f = (o-3)/7
__device__ __forceinline__ void up_coef(int o, int& i0, int& i1, float& t) {
    float f  = (float)(o - 3) * (1.0f / 7.0f);
    float fl = floorf(f);
    int   ii = (int)fl;
    t = f - fl;
    if (ii < 0)       { i0 = 0; i1 = 0; t = 0.0f; }
    else if (ii >= 7) { i0 = 7; i1 = 7; t = 0.0f; }
    else              { i0 = ii; i1 = ii + 1; }
}

// Split fp32 -> bf16 hi (truncate) + bf16 lo (truncate of exact remainder).
// hi+lo reproduces x to ~2^-17 relative; A*B via 3 MFMA terms ~2^-16.
__device__ __forceinline__ void split_bf16(float4 f, uint2& hi, uint2& lo) {
    unsigned u0 = __float_as_uint(f.x), u1 = __float_as_uint(f.y);
    unsigned u2 = __float_as_uint(f.z), u3 = __float_as_uint(f.w);
    unsigned h0 = u0 & 0xFFFF0000u, h1 = u1 & 0xFFFF0000u;
    unsigned h2 = u2 & 0xFFFF0000u, h3 = u3 & 0xFFFF0000u;
    hi = make_uint2((h0 >> 16) | h1, (h2 >> 16) | h3);
    float l0 = f.x - __uint_as_float(h0);
    float l1 = f.y - __uint_as_float(h1);
    float l2 = f.z - __uint_as_float(h2);
    float l3 = f.w - __uint_as_float(h3);
    lo = make_uint2((__float_as_uint(l0) >> 16) | (__float_as_uint(l1) & 0xFFFF0000u),
                    (__float_as_uint(l2) >> 16) | (__float_as_uint(l3) & 0xFFFF0000u));
}

// ---------------------------------------------------------------------------
// Prep: transpose dw weights [C][9] -> [9][C]; fold BN into scale/shift.
// ---------------------------------------------------------------------------
__global__ void prep_kernel(
    const float* __restrict__ w1, const float* __restrict__ w2, const float* __restrict__ w3,
    const float* __restrict__ g1, const float* __restrict__ b1, const float* __restrict__ m1, const float* __restrict__ v1,
    const float* __restrict__ g2, const float* __restrict__ b2, const float* __restrict__ m2, const float* __restrict__ v2,
    const float* __restrict__ g3, const float* __restrict__ b3, const float* __restrict__ m3, const float* __restrict__ v3,
    float* __restrict__ wT1, float* __restrict__ wT2, float* __restrict__ wT3,
    float* __restrict__ sc1, float* __restrict__ sh1,
    float* __restrict__ sc2, float* __restrict__ sh2,
    float* __restrict__ sc3, float* __restrict__ sh3)
{
    int c = threadIdx.x;   // 256 threads, 1 block
#pragma unroll
    for (int t = 0; t < 9; ++t) {
        wT1[t * C_ + c] = w1[c * 9 + t];
        wT2[t * C_ + c] = w2[c * 9 + t];
        wT3[t * C_ + c] = w3[c * 9 + t];
    }
    float s1 = g1[c] * rsqrtf(v1[c] + 1e-5f); sc1[c] = s1; sh1[c] = b1[c] - m1[c] * s1;
    float s2 = g2[c] * rsqrtf(v2[c] + 1e-5f); sc2[c] = s2; sh2[c] = b2[c] - m2[c] * s2;
    float s3 = g3[c] * rsqrtf(v3[c] + 1e-5f); sc3[c] = s3; sh3[c] = b3[c] - m3[c] * s3;
}

// ---------------------------------------------------------------------------
// MFMA GEMM (NT): C[m,n] = sum_k A[m,k]*Bm[n,k] (+bias[n]), fp32 in/out.
// Split-bf16: 3 MFMA terms (hi*hi + hi*lo + lo*hi) per fragment.
// BM=BN=128, BK=32, 256 thr (4 waves, 2x2), wave tile 64x64 (4x4 frags).
// LDS rows padded to 40 bf16 (20 dwords) -> 2-way bank aliasing (free).
// ---------------------------------------------------------------------------
#define AHI 0
#define ALO 2560
#define BHI 5120
#define BLO 7680
__global__ __launch_bounds__(256) void gemm_nt_mfma_kernel(
    const float* __restrict__ A,    // [M][K]
    const float* __restrict__ Bm,   // [N][K]
    const float* __restrict__ bias, // [N] or nullptr
    float* __restrict__ C,          // [M][N]
    int M, int N, int K)
{
    __shared__ unsigned lds[10240];   // 40 KB
    const int tid  = threadIdx.x;
    const int nb   = N >> 7;
    const int bx   = blockIdx.x % nb;
    const int by   = blockIdx.x / nb;
    const int lane = tid & 63;
    const int wv   = tid >> 6;        // wave 0..3
    const int wr   = wv >> 1, wc = wv & 1;
    const int l15  = lane & 15, kb = lane >> 4;

    const int srow = tid >> 1;             // 0..127
    const int sdw  = (tid & 1) * 8;        // dword offset within row (16 bf16)
    const float* Ap = A  + (size_t)(by * 128 + srow) * K + (tid & 1) * 16;
    const float* Bp = Bm + (size_t)(bx * 128 + srow) * K + (tid & 1) * 16;

    f32x4 acc[4][4];
#pragma unroll
    for (int m = 0; m < 4; ++m)
#pragma unroll
        for (int n = 0; n < 4; ++n) acc[m][n] = (f32x4)(0.0f);

    for (int k0 = 0; k0 < K; k0 += 32) {
        float4 a[4], b[4];
#pragma unroll
        for (int i = 0; i < 4; ++i) a[i] = *(const float4*)(Ap + k0 + i * 4);
#pragma unroll
        for (int i = 0; i < 4; ++i) b[i] = *(const float4*)(Bp + k0 + i * 4);
        __syncthreads();
        {
            uint2 h[4], l[4];
#pragma unroll
            for (int i = 0; i < 4; ++i) split_bf16(a[i], h[i], l[i]);
            *(uint4*)&lds[AHI + srow * 20 + sdw]     = make_uint4(h[0].x, h[0].y, h[1].x, h[1].y);
            *(uint4*)&lds[AHI + srow * 20 + sdw + 4] = make_uint4(h[2].x, h[2].y, h[3].x, h[3].y);
            *(uint4*)&lds[ALO + srow * 20 + sdw]     = make_uint4(l[0].x, l[0].y, l[1].x, l[1].y);
            *(uint4*)&lds[ALO + srow * 20 + sdw + 4] = make_uint4(l[2].x, l[2].y, l[3].x, l[3].y);
#pragma unroll
            for (int i = 0; i < 4; ++i) split_bf16(b[i], h[i], l[i]);
            *(uint4*)&lds[BHI + srow * 20 + sdw]     = make_uint4(h[0].x, h[0].y, h[1].x, h[1].y);
            *(uint4*)&lds[BHI + srow * 20 + sdw + 4] = make_uint4(h[2].x, h[2].y, h[3].x, h[3].y);
            *(uint4*)&lds[BLO + srow * 20 + sdw]     = make_uint4(l[0].x, l[0].y, l[1].x, l[1].y);
            *(uint4*)&lds[BLO + srow * 20 + sdw + 4] = make_uint4(l[2].x, l[2].y, l[3].x, l[3].y);
        }
        __syncthreads();

        bf16x8 ah[4], al[4], bh[4], bl[4];
#pragma unroll
        for (int m = 0; m < 4; ++m) {
            int r = wr * 64 + m * 16 + l15;
            ah[m] = *(const bf16x8*)&lds[AHI + r * 20 + kb * 4];
            al[m] = *(const bf16x8*)&lds[ALO + r * 20 + kb * 4];
        }
#pragma unroll
        for (int n = 0; n < 4; ++n) {
            int r = wc * 64 + n * 16 + l15;
            bh[n] = *(const bf16x8*)&lds[BHI + r * 20 + kb * 4];
            bl[n] = *(const bf16x8*)&lds[BLO + r * 20 + kb * 4];
        }
#pragma unroll
        for (int m = 0; m < 4; ++m)
#pragma unroll
            for (int n = 0; n < 4; ++n) {
                acc[m][n] = __builtin_amdgcn_mfma_f32_16x16x32_bf16(ah[m], bh[n], acc[m][n], 0, 0, 0);
                acc[m][n] = __builtin_amdgcn_mfma_f32_16x16x32_bf16(ah[m], bl[n], acc[m][n], 0, 0, 0);
                acc[m][n] = __builtin_amdgcn_mfma_f32_16x16x32_bf16(al[m], bh[n], acc[m][n], 0, 0, 0);
            }
    }

    // C/D layout (m89-verified): col = lane&15, row = (lane>>4)*4 + reg
    const int rb = by * 128 + wr * 64 + kb * 4;
    const int cb = bx * 128 + wc * 64 + l15;
#pragma unroll
    for (int n = 0; n < 4; ++n) {
        int col = cb + n * 16;
        float bv = bias ? bias[col] : 0.0f;
#pragma unroll
        for (int m = 0; m < 4; ++m) {
            int row = rb + m * 16;
#pragma unroll
            for (int r = 0; r < 4; ++r)
                C[(size_t)(row + r) * N + col] = acc[m][n][r] + bv;
        }
    }
}

// ---------------------------------------------------------------------------
// Fused: dwconv3x3 + BN, then (a) 7x7 avgpool of the BN output (pre-gelu)
// -> pool, and (b) gelu(BN output) -> outg (full res).
// Block = (b, gy, gx, chalf): one 7x7 pool window x 128 channels.
// Grid = 16*8*8*2 = 2048 blocks -> 8 blocks/CU (32 waves/CU, full occupancy).
// Thread map: lane&31 = channel-quad (of the half), (wv, lane>>5) = pixel slot.
// ---------------------------------------------------------------------------
__global__ __launch_bounds__(256, 8) void dwconv_bn_pool_gelu_kernel(
    const float* __restrict__ in,     // [B][56][56][C]
    const float* __restrict__ wT,     // [9][C]
    const float* __restrict__ scv,    // [C]
    const float* __restrict__ shv,    // [C]
    float* __restrict__ outg,         // [B][56][56][C]  gelu(bn(conv))
    float* __restrict__ pool)         // [B][64][C]      avgpool of bn(conv)
{
    const int blk   = blockIdx.x;
    const int ch    = blk & 1;            // channel half
    const int gx    = (blk >> 1) & 7;
    const int gy    = (blk >> 4) & 7;
    const int b     = blk >> 7;
    const int tid   = threadIdx.x;
    const int lane  = tid & 63;
    const int wv    = tid >> 6;
    const int c4h   = lane & 31;          // quad within the 128-ch half
    const int pslot = (wv << 1) | (lane >> 5);   // 0..7
    const int c0    = ch * 128 + c4h * 4;

    float4 wr[9];
#pragma unroll
    for (int t = 0; t < 9; ++t) wr[t] = *(const float4*)(wT + t * C_ + c0);
    const float4 sc = *(const float4*)(scv + c0);
    const float4 sh = *(const float4*)(shv + c0);

    const int x0 = gx * 7, y0 = gy * 7;
    const float* inb = in + (size_t)b * N_TOK * C_;
    float4 acc = make_float4(0, 0, 0, 0);

    for (int p = pslot; p < 49; p += 8) {
        int py = p / 7, px = p - py * 7;
        int y = y0 + py, x = x0 + px;
        float cx = 0.f, cy = 0.f, cz = 0.f, cw = 0.f;
#pragma unroll
        for (int dy = -1; dy <= 1; ++dy) {
            int yy = y + dy;
            if (yy < 0 || yy >= H_IMG) continue;
#pragma unroll
            for (int dx = -1; dx <= 1; ++dx) {
                int xx = x + dx;
                if (xx < 0 || xx >= W_IMG) continue;
                const float4 iv = *(const float4*)(inb + (size_t)(yy * W_IMG + xx) * C_ + c0);
                const float4 w  = wr[(dy + 1) * 3 + (dx + 1)];
                cx = fmaf(iv.x, w.x, cx);
                cy = fmaf(iv.y, w.y, cy);
                cz = fmaf(iv.z, w.z, cz);
                cw = fmaf(iv.w, w.w, cw);
            }
        }
        float vx = cx * sc.x + sh.x;
        float vy = cy * sc.y + sh.y;
        float vz = cz * sc.z + sh.z;
        float vw = cw * sc.w + sh.w;
        acc.x += vx; acc.y += vy; acc.z += vz; acc.w += vw;
        *(float4*)(outg + ((size_t)b * N_TOK + y * W_IMG + x) * C_ + c0) =
            make_float4(geluf(vx), geluf(vy), geluf(vz), geluf(vw));
    }

    __shared__ float4 ps[8][32];
    ps[pslot][c4h] = acc;
    __syncthreads();
    if (tid < 32) {
        float4 s = ps[0][tid];
#pragma unroll
        for (int t = 1; t < 8; ++t) {
            float4 u = ps[t][tid];
            s.x += u.x; s.y += u.y; s.z += u.z; s.w += u.w;
        }
        const float r = 1.0f / 49.0f;
        int g = gy * 8 + gx;
        *(float4*)(pool + ((size_t)b * 64 + g) * C_ + ch * 128 + tid * 4) =
            make_float4(s.x * r, s.y * r, s.z * r, s.w * r);
    }
}

// ---------------------------------------------------------------------------
// dwconv3x3 + BN + add (final conv). Weights in registers (fixed c4/thread).
// ---------------------------------------------------------------------------
__global__ __launch_bounds__(256, 8) void dwconv_bn_add_kernel(
    const float* __restrict__ in,     // [B][56][56][C]
    const float* __restrict__ wT,     // [9][C]
    const float* __restrict__ scv,    // [C]
    const float* __restrict__ shv,    // [C]
    const float* __restrict__ add_,   // [B][56][56][C]
    float* __restrict__ out)
{
    const int tid = threadIdx.x;
    const int c4  = tid & 63;
    const int wv  = tid >> 6;
    const int c0  = c4 * 4;
    float4 wr[9];
#pragma unroll
    for (int t = 0; t < 9; ++t) wr[t] = *(const float4*)(wT + t * C_ + c0);
    const float4 sc = *(const float4*)(scv + c0);
    const float4 sh = *(const float4*)(shv + c0);

    const int npix = B_ * N_TOK;
    for (int pix = blockIdx.x * 4 + wv; pix < npix; pix += gridDim.x * 4) {
        int bb  = pix / N_TOK;
        int rem = pix - bb * N_TOK;
        int y   = rem / W_IMG;
        int x   = rem - y * W_IMG;
        const float* inb = in + (size_t)bb * N_TOK * C_;
        float cx = 0.f, cy = 0.f, cz = 0.f, cw = 0.f;
#pragma unroll
        for (int dy = -1; dy <= 1; ++dy) {
            int yy = y + dy;
            if (yy < 0 || yy >= H_IMG) continue;
#pragma unroll
            for (int dx = -1; dx <= 1; ++dx) {
                int xx = x + dx;
                if (xx < 0 || xx >= W_IMG) continue;
                const float4 iv = *(const float4*)(inb + (size_t)(yy * W_IMG + xx) * C_ + c0);
                const float4 w  = wr[(dy + 1) * 3 + (dx + 1)];
                cx = fmaf(iv.x, w.x, cx);
                cy = fmaf(iv.y, w.y, cy);
                cz = fmaf(iv.z, w.z, cz);
                cw = fmaf(iv.w, w.w, cw);
            }
        }
        const float4 av = *(const float4*)(add_ + (size_t)pix * C_ + c0);
        *(float4*)(out + (size_t)pix * C_ + c0) = make_float4(
            cx * sc.x + sh.x + av.x, cy * sc.y + sh.y + av.y,
            cz * sc.z + sh.z + av.z, cw * sc.w + sh.w + av.w);
    }
}

// ---------------------------------------------------------------------------
// Per-(b,head) logits: A[i][j] = scale * dot32(q[b,i,h*32:], k[b,j,h*32:])
// ---------------------------------------------------------------------------
__global__ __launch_bounds__(256) void qk_kernel(
    const float* __restrict__ q,   // [B][64][C]
    const float* __restrict__ k,   // [B][64][C]
    float* __restrict__ attnL)     // [B*8][64][64]
{
    int bh = blockIdx.x;
    int b = bh >> 3, head = bh & 7;
    __shared__ float qs[64][33];
    __shared__ float ks[64][33];
    int tid = threadIdx.x;
    for (int t = tid; t < 512; t += 256) {
        int i = t >> 3, dq = (t & 7) * 4;
        const float4 qv = *(const float4*)(q + ((size_t)(b * 64 + i) * C_ + head * 32 + dq));
        const float4 kv = *(const float4*)(k + ((size_t)(b * 64 + i) * C_ + head * 32 + dq));
        qs[i][dq + 0] = qv.x; qs[i][dq + 1] = qv.y; qs[i][dq + 2] = qv.z; qs[i][dq + 3] = qv.w;
        ks[i][dq + 0] = kv.x; ks[i][dq + 1] = kv.y; ks[i][dq + 2] = kv.z; ks[i][dq + 3] = kv.w;
    }
    __syncthreads();
    int i  = tid >> 2;
    int jb = (tid & 3) * 16;
    float qr[32];
#pragma unroll
    for (int d = 0; d < 32; ++d) qr[d] = qs[i][d];
    float* outp = attnL + (size_t)bh * 4096 + i * 64 + jb;
#pragma unroll
    for (int j = 0; j < 16; ++j) {
        float s = 0.f;
#pragma unroll
        for (int d = 0; d < 32; ++d) s = fmaf(qr[d], ks[jb + j][d], s);
        outp[j] = s * 0.0625f;   // C^-0.5 = 1/16
    }
}

// ---------------------------------------------------------------------------
// Fused upsample(logits)->softmax-weights->PV partial sums.
// Block = (b, head, chunk of 7 image rows). Threads: 64 rows x 4 d-groups.
// Row max of upsampled logits == row max of raw logits (grid points exact,
// interp is convex) -> single pass, accumulate Z and o simultaneously.
// ---------------------------------------------------------------------------
__global__ __launch_bounds__(256) void attn_pv_kernel(
    const float* __restrict__ attnL,  // [BH][64][64]
    const float* __restrict__ v,      // [B][3136][256]
    float* __restrict__ part_o,       // [BH][NCH][64][32]
    float* __restrict__ part_z)       // [BH][NCH][64]
{
    int blk   = blockIdx.x;
    int chunk = blk % NCH;
    int bh    = blk / NCH;
    int b = bh >> 3, head = bh & 7;
    __shared__ float Al[64][64];
    __shared__ float mrow[64];
    __shared__ float RY[64][10];      // [i][0..8], entry 8 duplicates 7
    __shared__ float Vrow[56][32];
    __shared__ float txs[56];
    __shared__ int   x0s[56];
    int tid = threadIdx.x;

    {
        const float4* src = (const float4*)(attnL + (size_t)bh * 4096);
        float4* dst = (float4*)&Al[0][0];
        for (int t = tid; t < 1024; t += 256) dst[t] = src[t];
    }
    if (tid < 56) {
        int i0, i1; float t;
        up_coef(tid, i0, i1, t);
        x0s[tid] = i0;
        txs[tid] = t;
    }
    __syncthreads();
    if (tid < 64) {
        float m = Al[tid][0];
        for (int j = 1; j < 64; ++j) m = fmaxf(m, Al[tid][j]);
        mrow[tid] = m;
    }
    __syncthreads();

    int i  = tid >> 2;   // query row 0..63
    int dg = tid & 3;    // d-group (8 channels each)
    float4 o0 = make_float4(0,0,0,0), o1 = make_float4(0,0,0,0);
    float z = 0.f;

    for (int r = 0; r < 7; ++r) {
        int y = chunk * 7 + r;
        __syncthreads();   // protect Vrow/RY from previous iteration readers
        for (int t = tid; t < 448; t += 256) {
            int xx = t >> 3, dq = (t & 7) << 2;
            *(float4*)&Vrow[xx][dq] =
                *(const float4*)(v + ((size_t)b * N_TOK + y * W_IMG + xx) * C_ + head * 32 + dq);
        }
        int y0, y1; float ty;
        up_coef(y, y0, y1, ty);
        for (int kk = dg; kk < 9; kk += 4) {
            int ks = kk < 8 ? kk : 7;
            float a0 = Al[i][y0 * 8 + ks];
            float a1 = Al[i][y1 * 8 + ks];
            RY[i][kk] = a0 + ty * (a1 - a0) - mrow[i];
        }
        __syncthreads();
        for (int x = 0; x < 56; ++x) {
            float tx = txs[x];
            int   x0 = x0s[x];
            float r0 = RY[i][x0], r1 = RY[i][x0 + 1];
            float l = r0 + tx * (r1 - r0);
            float wgt = __expf(l);
            z += wgt;
            const float4 v0 = *(const float4*)&Vrow[x][dg * 8];
            const float4 v1 = *(const float4*)&Vrow[x][dg * 8 + 4];
            o0.x = fmaf(wgt, v0.x, o0.x); o0.y = fmaf(wgt, v0.y, o0.y);
            o0.z = fmaf(wgt, v0.z, o0.z); o0.w = fmaf(wgt, v0.w, o0.w);
            o1.x = fmaf(wgt, v1.x, o1.x); o1.y = fmaf(wgt, v1.y, o1.y);
            o1.z = fmaf(wgt, v1.z, o1.z); o1.w = fmaf(wgt, v1.w, o1.w);
        }
    }

    size_t base = (((size_t)bh * NCH + chunk) * 64 + i) * 32 + dg * 8;
    *(float4*)(part_o + base)     = o0;
    *(float4*)(part_o + base + 4) = o1;
    if (dg == 0) part_z[((size_t)bh * NCH + chunk) * 64 + i] = z;
}

// ---------------------------------------------------------------------------
// Combine partials -> o_small [B][64][C] (NHWC, c = head*32+d), divide by Z.
// ---------------------------------------------------------------------------
__global__ __launch_bounds__(256) void combine_kernel(
    const float* __restrict__ part_o, const float* __restrict__ part_z,
    float* __restrict__ o_small)
{
    int idx = blockIdx.x * 256 + threadIdx.x;  // B*64*C
    if (idx >= B_ * 64 * C_) return;
    int c = idx % C_;
    int g = (idx / C_) % 64;
    int b = idx / (C_ * 64);
    int head = c >> 5, d = c & 31;
    int bh = b * 8 + head;
    float oo = 0.f, zz = 0.f;
    for (int ch = 0; ch < NCH; ++ch) {
        oo += part_o[(((size_t)bh * NCH + ch) * 64 + g) * 32 + d];
        zz += part_z[((size_t)bh * NCH + ch) * 64 + g];
    }
    o_small[idx] = oo / zz;
}

// ---------------------------------------------------------------------------
// Bilinear upsample 8x8 -> 56x56, NHWC.
// ---------------------------------------------------------------------------
__global__ __launch_bounds__(256) void upsample7_kernel(
    const float* __restrict__ in,   // [B][8][8][C]
    float* __restrict__ out)        // [B][56][56][C]
{
    int idx = blockIdx.x * 256 + threadIdx.x;  // per float4
    int c4  = idx % C4_;
    int pix = idx / C4_;
    int x = pix % W_IMG;
    int y = (pix / W_IMG) % H_IMG;
    int b = pix / (W_IMG * H_IMG);
    if (b >= B_) return;
    int y0, y1, x0, x1; float ty, tx;
    up_coef(y, y0, y1, ty);
    up_coef(x, x0, x1, tx);
    const float* base = in + (size_t)b * 64 * C_ + c4 * 4;
    const float4 v00 = *(const float4*)(base + (y0 * 8 + x0) * C_);
    const float4 v01 = *(const float4*)(base + (y0 * 8 + x1) * C_);
    const float4 v10 = *(const float4*)(base + (y1 * 8 + x0) * C_);
    const float4 v11 = *(const float4*)(base + (y1 * 8 + x1) * C_);
    float r0x = v00.x + tx * (v01.x - v00.x), r1x = v10.x + tx * (v11.x - v10.x);
    float r0y = v00.y + tx * (v01.y - v00.y), r1y = v10.y + tx * (v11.y - v10.y);
    float r0z = v00.z + tx * (v01.z - v00.z), r1z = v10.z + tx * (v11.z - v10.z);
    float r0w = v00.w + tx * (v01.w - v00.w), r1w = v10.w + tx * (v11.w - v10.w);
    *(float4*)(out + (size_t)idx * 4) = make_float4(
        r0x + ty * (r1x - r0x), r0y + ty * (r1y - r0y),
        r0z + ty * (r1z - r0z), r0w + ty * (r1w - r0w));
}

// ---------------------------------------------------------------------------
extern "C" void kernel_launch(void* const* d_in, const int* in_sizes, int n_in,
                              void* d_out, int out_size, void* d_ws, size_t ws_size,
                              hipStream_t stream)
{
    const float* x    = (const float*)d_in[0];
    const float* Wv   = (const float*)d_in[1];
    const float* c1w  = (const float*)d_in[2];
    const float* b1g  = (const float*)d_in[3];
    const float* b1b  = (const float*)d_in[4];
    const float* b1m  = (const float*)d_in[5];
    const float* b1v  = (const float*)d_in[6];
    const float* c2w  = (const float*)d_in[7];
    const float* b2g  = (const float*)d_in[8];
    const float* b2b  = (const float*)d_in[9];
    const float* b2m  = (const float*)d_in[10];
    const float* b2v  = (const float*)d_in[11];
    const float* vupw = (const float*)d_in[12];
    const float* b3g  = (const float*)d_in[13];
    const float* b3b  = (const float*)d_in[14];
    const float* b3m  = (const float*)d_in[15];
    const float* b3v  = (const float*)d_in[16];
    const float* Wp   = (const float*)d_in[17];
    const float* bp   = (const float*)d_in[18];
    float* out = (float*)d_out;
    float* ws  = (float*)d_ws;

    const size_t SZ = (size_t)B_ * N_TOK * C_;      // 12,845,056 floats
    float* v       = ws;
    float* s1g     = v   + SZ;                       // gelu(bn1(conv1(v)))
    float* s2g     = s1g + SZ;                       // gelu(bn2(conv2(s1g))) = skip_tok
    float* q       = s2g + SZ;                       // B*64*C
    float* kk      = q  + (size_t)B_ * 64 * C_;
    float* attnL   = kk + (size_t)B_ * 64 * C_;      // B*8*64*64
    float* part_o  = attnL  + (size_t)B_ * 8 * 64 * 64;
    float* part_z  = part_o + (size_t)B_ * 8 * NCH * 64 * 32;
    float* o_small = part_z + (size_t)B_ * 8 * NCH * 64;
    float* wT1     = o_small + (size_t)B_ * 64 * C_;
    float* wT2     = wT1 + 9 * C_;
    float* wT3     = wT2 + 9 * C_;
    float* sc1     = wT3 + 9 * C_;
    float* sh1     = sc1 + C_;
    float* sc2     = sh1 + C_;
    float* sh2     = sc2 + C_;
    float* sc3     = sh2 + C_;
    float* sh3     = sc3 + C_;

    const int M = B_ * N_TOK;                        // 50176
    const int pix_blocks = B_ * N_TOK / 4;           // 12544

    // 0. fold BN, transpose weights
    prep_kernel<<<1, 256, 0, stream>>>(c1w, c2w, vupw,
        b1g, b1b, b1m, b1v, b2g, b2b, b2m, b2v, b3g, b3b, b3m, b3v,
        wT1, wT2, wT3, sc1, sh1, sc2, sh2, sc3, sh3);
    // 1. v = x @ Wv^T   (MFMA split-bf16)
    gemm_nt_mfma_kernel<<<(M / 128) * (C_ / 128), 256, 0, stream>>>(x, Wv, nullptr, v, M, C_, C_);
    // 2. s1g = gelu(bn1(conv1(v))), q = avgpool(bn1(conv1(v)))
    dwconv_bn_pool_gelu_kernel<<<2048, 256, 0, stream>>>(v, wT1, sc1, sh1, s1g, q);
    // 3. s2g = gelu(bn2(conv2(s1g))), k = avgpool(bn2(conv2(s1g)))
    dwconv_bn_pool_gelu_kernel<<<2048, 256, 0, stream>>>(s1g, wT2, sc2, sh2, s2g, kk);
    // 4. logits (scaled)
    qk_kernel<<<B_ * 8, 256, 0, stream>>>(q, kk, attnL);
    // 5. fused upsample+softmax-weights+PV partials
    attn_pv_kernel<<<B_ * 8 * NCH, 256, 0, stream>>>(attnL, v, part_o, part_z);
    // 6. combine -> o_small [B][8][8][C]
    combine_kernel<<<B_ * 64 * C_ / 256, 256, 0, stream>>>(part_o, part_z, o_small);
    // 7. upsample o_small -> full res (reuse s1g, dead after step 3)
    upsample7_kernel<<<pix_blocks, 256, 0, stream>>>(o_small, s1g);
    // 8. t = bn3(conv3(up)) + s2g   (into v, dead after step 5)
    dwconv_bn_add_kernel<<<2048, 256, 0, stream>>>(s1g, wT3, sc3, sh3, s2g, v);
    // 9. out = t @ Wp^T + bp   (MFMA split-bf16)
    gemm_nt_mfma_kernel<<<(M / 128) * (C_ / 128), 256, 0, stream>>>(v, Wp, bp, out, M, C_, C_);
}

// Round 5
// 291.756 us; speedup vs baseline: 1.2887x; 1.2887x over previous
//
#include <hip/hip_runtime.h>
#include <math.h>

// Problem constants (LocallyEnhancedAttention: B=16, N=3136, C=256, SR=7, HEADS=8)
#define B_     16
#define H_IMG  56
#define W_IMG  56
#define N_TOK  3136      // 56*56
#define C_     256
#define C4_    64        // C_/4
#define NHEAD  8
#define HDIM   32
#define NCH    8         // attn pixel chunks (each = 7 image rows = 392 pixels)

typedef float f32x4 __attribute__((ext_vector_type(4)));
typedef __bf16 bf16x8 __attribute__((ext_vector_type(8)));

__device__ __forceinline__ float geluf(float x) {
    // jax.nn.gelu(approximate=False) = x * 0.5 * (1 + erf(x/sqrt(2)))
    return 0.5f * x * (1.0f + erff(x * 0.70710678118654752f));
}

// 8 -> 56 bilinear (half-pixel + edge renormalize == index clamp).
// f = (o-3)/7
__device__ __forceinline__ void up_coef(int o, int& i0, int& i1, float& t) {
    float f  = (float)(o - 3) * (1.0f / 7.0f);
    float fl = floorf(f);
    int   ii = (int)fl;
    t = f - fl;
    if (ii < 0)       { i0 = 0; i1 = 0; t = 0.0f; }
    else if (ii >= 7) { i0 = 7; i1 = 7; t = 0.0f; }
    else              { i0 = ii; i1 = ii + 1; }
}

// Split fp32 -> bf16 hi (truncate) + bf16 lo (truncate of exact remainder).
// hi+lo reproduces x to ~2^-17 relative; A*B via 3 MFMA terms ~2^-16.
__device__ __forceinline__ void split_bf16(float4 f, uint2& hi, uint2& lo) {
    unsigned u0 = __float_as_uint(f.x), u1 = __float_as_uint(f.y);
    unsigned u2 = __float_as_uint(f.z), u3 = __float_as_uint(f.w);
    unsigned h0 = u0 & 0xFFFF0000u, h1 = u1 & 0xFFFF0000u;
    unsigned h2 = u2 & 0xFFFF0000u, h3 = u3 & 0xFFFF0000u;
    hi = make_uint2((h0 >> 16) | h1, (h2 >> 16) | h3);
    float l0 = f.x - __uint_as_float(h0);
    float l1 = f.y - __uint_as_float(h1);
    float l2 = f.z - __uint_as_float(h2);
    float l3 = f.w - __uint_as_float(h3);
    lo = make_uint2((__float_as_uint(l0) >> 16) | (__float_as_uint(l1) & 0xFFFF0000u),
                    (__float_as_uint(l2) >> 16) | (__float_as_uint(l3) & 0xFFFF0000u));
}

// ---------------------------------------------------------------------------
// Prep: transpose dw weights [C][9] -> [9][C]; fold BN into scale/shift.
// ---------------------------------------------------------------------------
__global__ void prep_kernel(
    const float* __restrict__ w1, const float* __restrict__ w2, const float* __restrict__ w3,
    const float* __restrict__ g1, const float* __restrict__ b1, const float* __restrict__ m1, const float* __restrict__ v1,
    const float* __restrict__ g2, const float* __restrict__ b2, const float* __restrict__ m2, const float* __restrict__ v2,
    const float* __restrict__ g3, const float* __restrict__ b3, const float* __restrict__ m3, const float* __restrict__ v3,
    float* __restrict__ wT1, float* __restrict__ wT2, float* __restrict__ wT3,
    float* __restrict__ sc1, float* __restrict__ sh1,
    float* __restrict__ sc2, float* __restrict__ sh2,
    float* __restrict__ sc3, float* __restrict__ sh3)
{
    int c = threadIdx.x;   // 256 threads, 1 block
#pragma unroll
    for (int t = 0; t < 9; ++t) {
        wT1[t * C_ + c] = w1[c * 9 + t];
        wT2[t * C_ + c] = w2[c * 9 + t];
        wT3[t * C_ + c] = w3[c * 9 + t];
    }
    float s1 = g1[c] * rsqrtf(v1[c] + 1e-5f); sc1[c] = s1; sh1[c] = b1[c] - m1[c] * s1;
    float s2 = g2[c] * rsqrtf(v2[c] + 1e-5f); sc2[c] = s2; sh2[c] = b2[c] - m2[c] * s2;
    float s3 = g3[c] * rsqrtf(v3[c] + 1e-5f); sc3[c] = s3; sh3[c] = b3[c] - m3[c] * s3;
}

// ---------------------------------------------------------------------------
// MFMA GEMM (NT): C[m,n] = sum_k A[m,k]*Bm[n,k] (+bias[n]), fp32 in/out.
// Split-bf16: 3 MFMA terms (hi*hi + hi*lo + lo*hi) per fragment.
// BM=BN=128, BK=32, 256 thr (4 waves, 2x2), wave tile 64x64 (4x4 frags).
// LDS rows padded to 40 bf16 (20 dwords) -> 2-way bank aliasing (free).
// ---------------------------------------------------------------------------
#define AHI 0
#define ALO 2560
#define BHI 5120
#define BLO 7680
__global__ __launch_bounds__(256) void gemm_nt_mfma_kernel(
    const float* __restrict__ A,    // [M][K]
    const float* __restrict__ Bm,   // [N][K]
    const float* __restrict__ bias, // [N] or nullptr
    float* __restrict__ C,          // [M][N]
    int M, int N, int K)
{
    __shared__ unsigned lds[10240];   // 40 KB
    const int tid  = threadIdx.x;
    const int nb   = N >> 7;
    const int bx   = blockIdx.x % nb;
    const int by   = blockIdx.x / nb;
    const int lane = tid & 63;
    const int wv   = tid >> 6;        // wave 0..3
    const int wr   = wv >> 1, wc = wv & 1;
    const int l15  = lane & 15, kb = lane >> 4;

    const int srow = tid >> 1;             // 0..127
    const int sdw  = (tid & 1) * 8;        // dword offset within row (16 bf16)
    const float* Ap = A  + (size_t)(by * 128 + srow) * K + (tid & 1) * 16;
    const float* Bp = Bm + (size_t)(bx * 128 + srow) * K + (tid & 1) * 16;

    f32x4 acc[4][4];
#pragma unroll
    for (int m = 0; m < 4; ++m)
#pragma unroll
        for (int n = 0; n < 4; ++n) acc[m][n] = (f32x4)(0.0f);

    for (int k0 = 0; k0 < K; k0 += 32) {
        float4 a[4], b[4];
#pragma unroll
        for (int i = 0; i < 4; ++i) a[i] = *(const float4*)(Ap + k0 + i * 4);
#pragma unroll
        for (int i = 0; i < 4; ++i) b[i] = *(const float4*)(Bp + k0 + i * 4);
        __syncthreads();
        {
            uint2 h[4], l[4];
#pragma unroll
            for (int i = 0; i < 4; ++i) split_bf16(a[i], h[i], l[i]);
            *(uint4*)&lds[AHI + srow * 20 + sdw]     = make_uint4(h[0].x, h[0].y, h[1].x, h[1].y);
            *(uint4*)&lds[AHI + srow * 20 + sdw + 4] = make_uint4(h[2].x, h[2].y, h[3].x, h[3].y);
            *(uint4*)&lds[ALO + srow * 20 + sdw]     = make_uint4(l[0].x, l[0].y, l[1].x, l[1].y);
            *(uint4*)&lds[ALO + srow * 20 + sdw + 4] = make_uint4(l[2].x, l[2].y, l[3].x, l[3].y);
#pragma unroll
            for (int i = 0; i < 4; ++i) split_bf16(b[i], h[i], l[i]);
            *(uint4*)&lds[BHI + srow * 20 + sdw]     = make_uint4(h[0].x, h[0].y, h[1].x, h[1].y);
            *(uint4*)&lds[BHI + srow * 20 + sdw + 4] = make_uint4(h[2].x, h[2].y, h[3].x, h[3].y);
            *(uint4*)&lds[BLO + srow * 20 + sdw]     = make_uint4(l[0].x, l[0].y, l[1].x, l[1].y);
            *(uint4*)&lds[BLO + srow * 20 + sdw + 4] = make_uint4(l[2].x, l[2].y, l[3].x, l[3].y);
        }
        __syncthreads();

        bf16x8 ah[4], al[4], bh[4], bl[4];
#pragma unroll
        for (int m = 0; m < 4; ++m) {
            int r = wr * 64 + m * 16 + l15;
            ah[m] = *(const bf16x8*)&lds[AHI + r * 20 + kb * 4];
            al[m] = *(const bf16x8*)&lds[ALO + r * 20 + kb * 4];
        }
#pragma unroll
        for (int n = 0; n < 4; ++n) {
            int r = wc * 64 + n * 16 + l15;
            bh[n] = *(const bf16x8*)&lds[BHI + r * 20 + kb * 4];
            bl[n] = *(const bf16x8*)&lds[BLO + r * 20 + kb * 4];
        }
#pragma unroll
        for (int m = 0; m < 4; ++m)
#pragma unroll
            for (int n = 0; n < 4; ++n) {
                acc[m][n] = __builtin_amdgcn_mfma_f32_16x16x32_bf16(ah[m], bh[n], acc[m][n], 0, 0, 0);
                acc[m][n] = __builtin_amdgcn_mfma_f32_16x16x32_bf16(ah[m], bl[n], acc[m][n], 0, 0, 0);
                acc[m][n] = __builtin_amdgcn_mfma_f32_16x16x32_bf16(al[m], bh[n], acc[m][n], 0, 0, 0);
            }
    }

    // C/D layout (m89-verified): col = lane&15, row = (lane>>4)*4 + reg
    const int rb = by * 128 + wr * 64 + kb * 4;
    const int cb = bx * 128 + wc * 64 + l15;
#pragma unroll
    for (int n = 0; n < 4; ++n) {
        int col = cb + n * 16;
        float bv = bias ? bias[col] : 0.0f;
#pragma unroll
        for (int m = 0; m < 4; ++m) {
            int row = rb + m * 16;
#pragma unroll
            for (int r = 0; r < 4; ++r)
                C[(size_t)(row + r) * N + col] = acc[m][n][r] + bv;
        }
    }
}

// ---------------------------------------------------------------------------
// Fused: dwconv3x3 + BN, then (a) 7x7 avgpool of BN output -> pool, and
// (b) gelu(BN output) -> outg (full res).
// Block = one 7x7 pool window x 256 channels. Grid = 16*64 = 1024
// (4 blocks/CU, 16 waves/CU). XCD-aware decode: blk&7 = XCD slot; each XCD
// gets 2 whole images -> halo re-reads hit that XCD's private L2
// (one image input = 3.2 MB < 4 MB L2/XCD).
// Thread map: c4 = tid&63 (wave = full 1KB pixel), wv = pixel slot.
// ---------------------------------------------------------------------------
__global__ __launch_bounds__(256, 4) void dwconv_bn_pool_gelu_kernel(
    const float* __restrict__ in,     // [B][56][56][C]
    const float* __restrict__ wT,     // [9][C]
    const float* __restrict__ scv,    // [C]
    const float* __restrict__ shv,    // [C]
    float* __restrict__ outg,         // [B][56][56][C]  gelu(bn(conv))
    float* __restrict__ pool)         // [B][64][C]      avgpool of bn(conv)
{
    const int blk = blockIdx.x;
    const int xcd = blk & 7;
    const int j   = blk >> 3;             // 0..127
    const int b   = xcd + 8 * (j >> 6);   // each XCD: 2 whole images
    const int g   = j & 63;
    const int gy  = g >> 3, gx = g & 7;
    const int tid = threadIdx.x;
    const int c4  = tid & 63;
    const int wv  = tid >> 6;
    const int c0  = c4 * 4;

    float4 wr[9];
#pragma unroll
    for (int t = 0; t < 9; ++t) wr[t] = *(const float4*)(wT + t * C_ + c0);
    const float4 sc = *(const float4*)(scv + c0);
    const float4 sh = *(const float4*)(shv + c0);

    const int x0 = gx * 7, y0 = gy * 7;
    const float* inb = in + (size_t)b * N_TOK * C_;
    float4 acc = make_float4(0, 0, 0, 0);

    for (int p = wv; p < 49; p += 4) {
        int py = p / 7, px = p - py * 7;
        int y = y0 + py, x = x0 + px;
        float cx = 0.f, cy = 0.f, cz = 0.f, cw = 0.f;
#pragma unroll
        for (int dy = -1; dy <= 1; ++dy) {
            int yy = y + dy;
            if (yy < 0 || yy >= H_IMG) continue;
#pragma unroll
            for (int dx = -1; dx <= 1; ++dx) {
                int xx = x + dx;
                if (xx < 0 || xx >= W_IMG) continue;
                const float4 iv = *(const float4*)(inb + (size_t)(yy * W_IMG + xx) * C_ + c0);
                const float4 w  = wr[(dy + 1) * 3 + (dx + 1)];
                cx = fmaf(iv.x, w.x, cx);
                cy = fmaf(iv.y, w.y, cy);
                cz = fmaf(iv.z, w.z, cz);
                cw = fmaf(iv.w, w.w, cw);
            }
        }
        float vx = cx * sc.x + sh.x;
        float vy = cy * sc.y + sh.y;
        float vz = cz * sc.z + sh.z;
        float vw = cw * sc.w + sh.w;
        acc.x += vx; acc.y += vy; acc.z += vz; acc.w += vw;
        *(float4*)(outg + ((size_t)b * N_TOK + y * W_IMG + x) * C_ + c0) =
            make_float4(geluf(vx), geluf(vy), geluf(vz), geluf(vw));
    }

    __shared__ float4 ps[4][64];
    ps[wv][c4] = acc;
    __syncthreads();
    if (tid < 64) {
        float4 s  = ps[0][tid];
        float4 t1 = ps[1][tid];
        float4 t2 = ps[2][tid];
        float4 t3 = ps[3][tid];
        const float r = 1.0f / 49.0f;
        *(float4*)(pool + ((size_t)b * 64 + g) * C_ + tid * 4) = make_float4(
            (s.x + t1.x + t2.x + t3.x) * r, (s.y + t1.y + t2.y + t3.y) * r,
            (s.z + t1.z + t2.z + t3.z) * r, (s.w + t1.w + t2.w + t3.w) * r);
    }
}

// ---------------------------------------------------------------------------
// dwconv3x3 + BN + add (final conv). Same window blocking + XCD decode as
// pool_gelu (no pool). Weights in registers.
// ---------------------------------------------------------------------------
__global__ __launch_bounds__(256, 4) void dwconv_bn_add_kernel(
    const float* __restrict__ in,     // [B][56][56][C]
    const float* __restrict__ wT,     // [9][C]
    const float* __restrict__ scv,    // [C]
    const float* __restrict__ shv,    // [C]
    const float* __restrict__ add_,   // [B][56][56][C]
    float* __restrict__ out)
{
    const int blk = blockIdx.x;
    const int xcd = blk & 7;
    const int j   = blk >> 3;
    const int b   = xcd + 8 * (j >> 6);
    const int g   = j & 63;
    const int gy  = g >> 3, gx = g & 7;
    const int tid = threadIdx.x;
    const int c4  = tid & 63;
    const int wv  = tid >> 6;
    const int c0  = c4 * 4;

    float4 wr[9];
#pragma unroll
    for (int t = 0; t < 9; ++t) wr[t] = *(const float4*)(wT + t * C_ + c0);
    const float4 sc = *(const float4*)(scv + c0);
    const float4 sh = *(const float4*)(shv + c0);

    const int x0 = gx * 7, y0 = gy * 7;
    const float* inb = in + (size_t)b * N_TOK * C_;

    for (int p = wv; p < 49; p += 4) {
        int py = p / 7, px = p - py * 7;
        int y = y0 + py, x = x0 + px;
        float cx = 0.f, cy = 0.f, cz = 0.f, cw = 0.f;
#pragma unroll
        for (int dy = -1; dy <= 1; ++dy) {
            int yy = y + dy;
            if (yy < 0 || yy >= H_IMG) continue;
#pragma unroll
            for (int dx = -1; dx <= 1; ++dx) {
                int xx = x + dx;
                if (xx < 0 || xx >= W_IMG) continue;
                const float4 iv = *(const float4*)(inb + (size_t)(yy * W_IMG + xx) * C_ + c0);
                const float4 w  = wr[(dy + 1) * 3 + (dx + 1)];
                cx = fmaf(iv.x, w.x, cx);
                cy = fmaf(iv.y, w.y, cy);
                cz = fmaf(iv.z, w.z, cz);
                cw = fmaf(iv.w, w.w, cw);
            }
        }
        size_t pix = (size_t)b * N_TOK + y * W_IMG + x;
        const float4 av = *(const float4*)(add_ + pix * C_ + c0);
        *(float4*)(out + pix * C_ + c0) = make_float4(
            cx * sc.x + sh.x + av.x, cy * sc.y + sh.y + av.y,
            cz * sc.z + sh.z + av.z, cw * sc.w + sh.w + av.w);
    }
}

// ---------------------------------------------------------------------------
// Per-(b,head) logits: A[i][j] = scale * dot32(q[b,i,h*32:], k[b,j,h*32:])
// ---------------------------------------------------------------------------
__global__ __launch_bounds__(256) void qk_kernel(
    const float* __restrict__ q,   // [B][64][C]
    const float* __restrict__ k,   // [B][64][C]
    float* __restrict__ attnL)     // [B*8][64][64]
{
    int bh = blockIdx.x;
    int b = bh >> 3, head = bh & 7;
    __shared__ float qs[64][33];
    __shared__ float ks[64][33];
    int tid = threadIdx.x;
    for (int t = tid; t < 512; t += 256) {
        int i = t >> 3, dq = (t & 7) * 4;
        const float4 qv = *(const float4*)(q + ((size_t)(b * 64 + i) * C_ + head * 32 + dq));
        const float4 kv = *(const float4*)(k + ((size_t)(b * 64 + i) * C_ + head * 32 + dq));
        qs[i][dq + 0] = qv.x; qs[i][dq + 1] = qv.y; qs[i][dq + 2] = qv.z; qs[i][dq + 3] = qv.w;
        ks[i][dq + 0] = kv.x; ks[i][dq + 1] = kv.y; ks[i][dq + 2] = kv.z; ks[i][dq + 3] = kv.w;
    }
    __syncthreads();
    int i  = tid >> 2;
    int jb = (tid & 3) * 16;
    float qr[32];
#pragma unroll
    for (int d = 0; d < 32; ++d) qr[d] = qs[i][d];
    float* outp = attnL + (size_t)bh * 4096 + i * 64 + jb;
#pragma unroll
    for (int j = 0; j < 16; ++j) {
        float s = 0.f;
#pragma unroll
        for (int d = 0; d < 32; ++d) s = fmaf(qr[d], ks[jb + j][d], s);
        outp[j] = s * 0.0625f;   // C^-0.5 = 1/16
    }
}

// ---------------------------------------------------------------------------
// Fused upsample(logits)->softmax-weights->PV partial sums.
// Block = (b, head, chunk of 7 image rows). Threads: 64 rows x 4 d-groups.
// Row max of upsampled logits == row max of raw logits (grid points exact,
// interp is convex) -> single pass, accumulate Z and o simultaneously.
// ---------------------------------------------------------------------------
__global__ __launch_bounds__(256) void attn_pv_kernel(
    const float* __restrict__ attnL,  // [BH][64][64]
    const float* __restrict__ v,      // [B][3136][256]
    float* __restrict__ part_o,       // [BH][NCH][64][32]
    float* __restrict__ part_z)       // [BH][NCH][64]
{
    int blk   = blockIdx.x;
    int chunk = blk % NCH;
    int bh    = blk / NCH;
    int b = bh >> 3, head = bh & 7;
    __shared__ float Al[64][64];
    __shared__ float mrow[64];
    __shared__ float RY[64][10];      // [i][0..8], entry 8 duplicates 7
    __shared__ float Vrow[56][32];
    __shared__ float txs[56];
    __shared__ int   x0s[56];
    int tid = threadIdx.x;

    {
        const float4* src = (const float4*)(attnL + (size_t)bh * 4096);
        float4* dst = (float4*)&Al[0][0];
        for (int t = tid; t < 1024; t += 256) dst[t] = src[t];
    }
    if (tid < 56) {
        int i0, i1; float t;
        up_coef(tid, i0, i1, t);
        x0s[tid] = i0;
        txs[tid] = t;
    }
    __syncthreads();
    if (tid < 64) {
        float m = Al[tid][0];
        for (int j = 1; j < 64; ++j) m = fmaxf(m, Al[tid][j]);
        mrow[tid] = m;
    }
    __syncthreads();

    int i  = tid >> 2;   // query row 0..63
    int dg = tid & 3;    // d-group (8 channels each)
    float4 o0 = make_float4(0,0,0,0), o1 = make_float4(0,0,0,0);
    float z = 0.f;

    for (int r = 0; r < 7; ++r) {
        int y = chunk * 7 + r;
        __syncthreads();   // protect Vrow/RY from previous iteration readers
        for (int t = tid; t < 448; t += 256) {
            int xx = t >> 3, dq = (t & 7) << 2;
            *(float4*)&Vrow[xx][dq] =
                *(const float4*)(v + ((size_t)b * N_TOK + y * W_IMG + xx) * C_ + head * 32 + dq);
        }
        int y0, y1; float ty;
        up_coef(y, y0, y1, ty);
        for (int kk = dg; kk < 9; kk += 4) {
            int ks = kk < 8 ? kk : 7;
            float a0 = Al[i][y0 * 8 + ks];
            float a1 = Al[i][y1 * 8 + ks];
            RY[i][kk] = a0 + ty * (a1 - a0) - mrow[i];
        }
        __syncthreads();
        for (int x = 0; x < 56; ++x) {
            float tx = txs[x];
            int   x0 = x0s[x];
            float r0 = RY[i][x0], r1 = RY[i][x0 + 1];
            float l = r0 + tx * (r1 - r0);
            float wgt = __expf(l);
            z += wgt;
            const float4 v0 = *(const float4*)&Vrow[x][dg * 8];
            const float4 v1 = *(const float4*)&Vrow[x][dg * 8 + 4];
            o0.x = fmaf(wgt, v0.x, o0.x); o0.y = fmaf(wgt, v0.y, o0.y);
            o0.z = fmaf(wgt, v0.z, o0.z); o0.w = fmaf(wgt, v0.w, o0.w);
            o1.x = fmaf(wgt, v1.x, o1.x); o1.y = fmaf(wgt, v1.y, o1.y);
            o1.z = fmaf(wgt, v1.z, o1.z); o1.w = fmaf(wgt, v1.w, o1.w);
        }
    }

    size_t base = (((size_t)bh * NCH + chunk) * 64 + i) * 32 + dg * 8;
    *(float4*)(part_o + base)     = o0;
    *(float4*)(part_o + base + 4) = o1;
    if (dg == 0) part_z[((size_t)bh * NCH + chunk) * 64 + i] = z;
}

// ---------------------------------------------------------------------------
// Combine partials -> o_small [B][64][C] (NHWC, c = head*32+d), divide by Z.
// ---------------------------------------------------------------------------
__global__ __launch_bounds__(256) void combine_kernel(
    const float* __restrict__ part_o, const float* __restrict__ part_z,
    float* __restrict__ o_small)
{
    int idx = blockIdx.x * 256 + threadIdx.x;  // B*64*C
    if (idx >= B_ * 64 * C_) return;
    int c = idx % C_;
    int g = (idx / C_) % 64;
    int b = idx / (C_ * 64);
    int head = c >> 5, d = c & 31;
    int bh = b * 8 + head;
    float oo = 0.f, zz = 0.f;
    for (int ch = 0; ch < NCH; ++ch) {
        oo += part_o[(((size_t)bh * NCH + ch) * 64 + g) * 32 + d];
        zz += part_z[((size_t)bh * NCH + ch) * 64 + g];
    }
    o_small[idx] = oo / zz;
}

// ---------------------------------------------------------------------------
// Bilinear upsample 8x8 -> 56x56, NHWC.
// ---------------------------------------------------------------------------
__global__ __launch_bounds__(256) void upsample7_kernel(
    const float* __restrict__ in,   // [B][8][8][C]
    float* __restrict__ out)        // [B][56][56][C]
{
    int idx = blockIdx.x * 256 + threadIdx.x;  // per float4
    int c4  = idx % C4_;
    int pix = idx / C4_;
    int x = pix % W_IMG;
    int y = (pix / W_IMG) % H_IMG;
    int b = pix / (W_IMG * H_IMG);
    if (b >= B_) return;
    int y0, y1, x0, x1; float ty, tx;
    up_coef(y, y0, y1, ty);
    up_coef(x, x0, x1, tx);
    const float* base = in + (size_t)b * 64 * C_ + c4 * 4;
    const float4 v00 = *(const float4*)(base + (y0 * 8 + x0) * C_);
    const float4 v01 = *(const float4*)(base + (y0 * 8 + x1) * C_);
    const float4 v10 = *(const float4*)(base + (y1 * 8 + x0) * C_);
    const float4 v11 = *(const float4*)(base + (y1 * 8 + x1) * C_);
    float r0x = v00.x + tx * (v01.x - v00.x), r1x = v10.x + tx * (v11.x - v10.x);
    float r0y = v00.y + tx * (v01.y - v00.y), r1y = v10.y + tx * (v11.y - v10.y);
    float r0z = v00.z + tx * (v01.z - v00.z), r1z = v10.z + tx * (v11.z - v10.z);
    float r0w = v00.w + tx * (v01.w - v00.w), r1w = v10.w + tx * (v11.w - v10.w);
    *(float4*)(out + (size_t)idx * 4) = make_float4(
        r0x + ty * (r1x - r0x), r0y + ty * (r1y - r0y),
        r0z + ty * (r1z - r0z), r0w + ty * (r1w - r0w));
}

// ---------------------------------------------------------------------------
extern "C" void kernel_launch(void* const* d_in, const int* in_sizes, int n_in,
                              void* d_out, int out_size, void* d_ws, size_t ws_size,
                              hipStream_t stream)
{
    const float* x    = (const float*)d_in[0];
    const float* Wv   = (const float*)d_in[1];
    const float* c1w  = (const float*)d_in[2];
    const float* b1g  = (const float*)d_in[3];
    const float* b1b  = (const float*)d_in[4];
    const float* b1m  = (const float*)d_in[5];
    const float* b1v  = (const float*)d_in[6];
    const float* c2w  = (const float*)d_in[7];
    const float* b2g  = (const float*)d_in[8];
    const float* b2b  = (const float*)d_in[9];
    const float* b2m  = (const float*)d_in[10];
    const float* b2v  = (const float*)d_in[11];
    const float* vupw = (const float*)d_in[12];
    const float* b3g  = (const float*)d_in[13];
    const float* b3b  = (const float*)d_in[14];
    const float* b3m  = (const float*)d_in[15];
    const float* b3v  = (const float*)d_in[16];
    const float* Wp   = (const float*)d_in[17];
    const float* bp   = (const float*)d_in[18];
    float* out = (float*)d_out;
    float* ws  = (float*)d_ws;

    const size_t SZ = (size_t)B_ * N_TOK * C_;      // 12,845,056 floats
    float* v       = ws;
    float* s1g     = v   + SZ;                       // gelu(bn1(conv1(v)))
    float* s2g     = s1g + SZ;                       // gelu(bn2(conv2(s1g))) = skip_tok
    float* q       = s2g + SZ;                       // B*64*C
    float* kk      = q  + (size_t)B_ * 64 * C_;
    float* attnL   = kk + (size_t)B_ * 64 * C_;      // B*8*64*64
    float* part_o  = attnL  + (size_t)B_ * 8 * 64 * 64;
    float* part_z  = part_o + (size_t)B_ * 8 * NCH * 64 * 32;
    float* o_small = part_z + (size_t)B_ * 8 * NCH * 64;
    float* wT1     = o_small + (size_t)B_ * 64 * C_;
    float* wT2     = wT1 + 9 * C_;
    float* wT3     = wT2 + 9 * C_;
    float* sc1     = wT3 + 9 * C_;
    float* sh1     = sc1 + C_;
    float* sc2     = sh1 + C_;
    float* sh2     = sc2 + C_;
    float* sc3     = sh2 + C_;
    float* sh3     = sc3 + C_;

    const int M = B_ * N_TOK;                        // 50176
    const int pix_blocks = B_ * N_TOK / 4;           // 12544

    // 0. fold BN, transpose weights
    prep_kernel<<<1, 256, 0, stream>>>(c1w, c2w, vupw,
        b1g, b1b, b1m, b1v, b2g, b2b, b2m, b2v, b3g, b3b, b3m, b3v,
        wT1, wT2, wT3, sc1, sh1, sc2, sh2, sc3, sh3);
    // 1. v = x @ Wv^T   (MFMA split-bf16)
    gemm_nt_mfma_kernel<<<(M / 128) * (C_ / 128), 256, 0, stream>>>(x, Wv, nullptr, v, M, C_, C_);
    // 2. s1g = gelu(bn1(conv1(v))), q = avgpool(bn1(conv1(v)))
    dwconv_bn_pool_gelu_kernel<<<1024, 256, 0, stream>>>(v, wT1, sc1, sh1, s1g, q);
    // 3. s2g = gelu(bn2(conv2(s1g))), k = avgpool(bn2(conv2(s1g)))
    dwconv_bn_pool_gelu_kernel<<<1024, 256, 0, stream>>>(s1g, wT2, sc2, sh2, s2g, kk);
    // 4. logits (scaled)
    qk_kernel<<<B_ * 8, 256, 0, stream>>>(q, kk, attnL);
    // 5. fused upsample+softmax-weights+PV partials
    attn_pv_kernel<<<B_ * 8 * NCH, 256, 0, stream>>>(attnL, v, part_o, part_z);
    // 6. combine -> o_small [B][8][8][C]
    combine_kernel<<<B_ * 64 * C_ / 256, 256, 0, stream>>>(part_o, part_z, o_small);
    // 7. upsample o_small -> full res (reuse s1g, dead after step 3)
    upsample7_kernel<<<pix_blocks, 256, 0, stream>>>(o_small, s1g);
    // 8. t = bn3(conv3(up)) + s2g   (into v, dead after step 5)
    dwconv_bn_add_kernel<<<1024, 256, 0, stream>>>(s1g, wT3, sc3, sh3, s2g, v);
    // 9. out = t @ Wp^T + bp   (MFMA split-bf16)
    gemm_nt_mfma_kernel<<<(M / 128) * (C_ / 128), 256, 0, stream>>>(v, Wp, bp, out, M, C_, C_);
}

// Round 6
// 253.124 us; speedup vs baseline: 1.4854x; 1.1526x over previous
//
#include <hip/hip_runtime.h>
#include <math.h>

// Problem constants (LocallyEnhancedAttention: B=16, N=3136, C=256, SR=7, HEADS=8)
#define B_     16
#define H_IMG  56
#define W_IMG  56
#define N_TOK  3136      // 56*56
#define C_     256
#define C4_    64        // C_/4
#define NHEAD  8
#define HDIM   32
#define NCH    8         // attn chunks (each = 7 image rows)

typedef float f32x4 __attribute__((ext_vector_type(4)));
typedef __bf16 bf16x8 __attribute__((ext_vector_type(8)));

__device__ __forceinline__ float geluf(float x) {
    return 0.5f * x * (1.0f + erff(x * 0.70710678118654752f));
}

// 8 -> 56 bilinear (half-pixel + edge renormalize == index clamp). f = (o-3)/7
__device__ __forceinline__ void up_coef(int o, int& i0, int& i1, float& t) {
    float f  = (float)(o - 3) * (1.0f / 7.0f);
    float fl = floorf(f);
    int   ii = (int)fl;
    t = f - fl;
    if (ii < 0)       { i0 = 0; i1 = 0; t = 0.0f; }
    else if (ii >= 7) { i0 = 7; i1 = 7; t = 0.0f; }
    else              { i0 = ii; i1 = ii + 1; }
}

__device__ __forceinline__ void split_bf16(float4 f, uint2& hi, uint2& lo) {
    unsigned u0 = __float_as_uint(f.x), u1 = __float_as_uint(f.y);
    unsigned u2 = __float_as_uint(f.z), u3 = __float_as_uint(f.w);
    unsigned h0 = u0 & 0xFFFF0000u, h1 = u1 & 0xFFFF0000u;
    unsigned h2 = u2 & 0xFFFF0000u, h3 = u3 & 0xFFFF0000u;
    hi = make_uint2((h0 >> 16) | h1, (h2 >> 16) | h3);
    float l0 = f.x - __uint_as_float(h0);
    float l1 = f.y - __uint_as_float(h1);
    float l2 = f.z - __uint_as_float(h2);
    float l3 = f.w - __uint_as_float(h3);
    lo = make_uint2((__float_as_uint(l0) >> 16) | (__float_as_uint(l1) & 0xFFFF0000u),
                    (__float_as_uint(l2) >> 16) | (__float_as_uint(l3) & 0xFFFF0000u));
}

__device__ __forceinline__ unsigned pack2_bf16(float a, float b) {
    __bf16 ha = (__bf16)a, hb = (__bf16)b;   // RNE; compiler emits cvt
    unsigned short ua = __builtin_bit_cast(unsigned short, ha);
    unsigned short ub = __builtin_bit_cast(unsigned short, hb);
    return (unsigned)ua | ((unsigned)ub << 16);
}

// ---------------------------------------------------------------------------
// Prep: transpose dw weights [C][9] -> [9][C]; fold BN into scale/shift.
// ---------------------------------------------------------------------------
__global__ void prep_kernel(
    const float* __restrict__ w1, const float* __restrict__ w2, const float* __restrict__ w3,
    const float* __restrict__ g1, const float* __restrict__ b1, const float* __restrict__ m1, const float* __restrict__ v1,
    const float* __restrict__ g2, const float* __restrict__ b2, const float* __restrict__ m2, const float* __restrict__ v2,
    const float* __restrict__ g3, const float* __restrict__ b3, const float* __restrict__ m3, const float* __restrict__ v3,
    float* __restrict__ wT1, float* __restrict__ wT2, float* __restrict__ wT3,
    float* __restrict__ sc1, float* __restrict__ sh1,
    float* __restrict__ sc2, float* __restrict__ sh2,
    float* __restrict__ sc3, float* __restrict__ sh3)
{
    int c = threadIdx.x;
#pragma unroll
    for (int t = 0; t < 9; ++t) {
        wT1[t * C_ + c] = w1[c * 9 + t];
        wT2[t * C_ + c] = w2[c * 9 + t];
        wT3[t * C_ + c] = w3[c * 9 + t];
    }
    float s1 = g1[c] * rsqrtf(v1[c] + 1e-5f); sc1[c] = s1; sh1[c] = b1[c] - m1[c] * s1;
    float s2 = g2[c] * rsqrtf(v2[c] + 1e-5f); sc2[c] = s2; sh2[c] = b2[c] - m2[c] * s2;
    float s3 = g3[c] * rsqrtf(v3[c] + 1e-5f); sc3[c] = s3; sh3[c] = b3[c] - m3[c] * s3;
}

// ---------------------------------------------------------------------------
// MFMA GEMM (NT), split-bf16 (unchanged from R3/R5 — verified).
// ---------------------------------------------------------------------------
#define AHI 0
#define ALO 2560
#define BHI 5120
#define BLO 7680
__global__ __launch_bounds__(256) void gemm_nt_mfma_kernel(
    const float* __restrict__ A, const float* __restrict__ Bm,
    const float* __restrict__ bias, float* __restrict__ C,
    int M, int N, int K)
{
    __shared__ unsigned lds[10240];
    const int tid  = threadIdx.x;
    const int nb   = N >> 7;
    const int bx   = blockIdx.x % nb;
    const int by   = blockIdx.x / nb;
    const int lane = tid & 63;
    const int wv   = tid >> 6;
    const int wr   = wv >> 1, wc = wv & 1;
    const int l15  = lane & 15, kb = lane >> 4;

    const int srow = tid >> 1;
    const int sdw  = (tid & 1) * 8;
    const float* Ap = A  + (size_t)(by * 128 + srow) * K + (tid & 1) * 16;
    const float* Bp = Bm + (size_t)(bx * 128 + srow) * K + (tid & 1) * 16;

    f32x4 acc[4][4];
#pragma unroll
    for (int m = 0; m < 4; ++m)
#pragma unroll
        for (int n = 0; n < 4; ++n) acc[m][n] = (f32x4)(0.0f);

    for (int k0 = 0; k0 < K; k0 += 32) {
        float4 a[4], b[4];
#pragma unroll
        for (int i = 0; i < 4; ++i) a[i] = *(const float4*)(Ap + k0 + i * 4);
#pragma unroll
        for (int i = 0; i < 4; ++i) b[i] = *(const float4*)(Bp + k0 + i * 4);
        __syncthreads();
        {
            uint2 h[4], l[4];
#pragma unroll
            for (int i = 0; i < 4; ++i) split_bf16(a[i], h[i], l[i]);
            *(uint4*)&lds[AHI + srow * 20 + sdw]     = make_uint4(h[0].x, h[0].y, h[1].x, h[1].y);
            *(uint4*)&lds[AHI + srow * 20 + sdw + 4] = make_uint4(h[2].x, h[2].y, h[3].x, h[3].y);
            *(uint4*)&lds[ALO + srow * 20 + sdw]     = make_uint4(l[0].x, l[0].y, l[1].x, l[1].y);
            *(uint4*)&lds[ALO + srow * 20 + sdw + 4] = make_uint4(l[2].x, l[2].y, l[3].x, l[3].y);
#pragma unroll
            for (int i = 0; i < 4; ++i) split_bf16(b[i], h[i], l[i]);
            *(uint4*)&lds[BHI + srow * 20 + sdw]     = make_uint4(h[0].x, h[0].y, h[1].x, h[1].y);
            *(uint4*)&lds[BHI + srow * 20 + sdw + 4] = make_uint4(h[2].x, h[2].y, h[3].x, h[3].y);
            *(uint4*)&lds[BLO + srow * 20 + sdw]     = make_uint4(l[0].x, l[0].y, l[1].x, l[1].y);
            *(uint4*)&lds[BLO + srow * 20 + sdw + 4] = make_uint4(l[2].x, l[2].y, l[3].x, l[3].y);
        }
        __syncthreads();

        bf16x8 ah[4], al[4], bh[4], bl[4];
#pragma unroll
        for (int m = 0; m < 4; ++m) {
            int r = wr * 64 + m * 16 + l15;
            ah[m] = *(const bf16x8*)&lds[AHI + r * 20 + kb * 4];
            al[m] = *(const bf16x8*)&lds[ALO + r * 20 + kb * 4];
        }
#pragma unroll
        for (int n = 0; n < 4; ++n) {
            int r = wc * 64 + n * 16 + l15;
            bh[n] = *(const bf16x8*)&lds[BHI + r * 20 + kb * 4];
            bl[n] = *(const bf16x8*)&lds[BLO + r * 20 + kb * 4];
        }
#pragma unroll
        for (int m = 0; m < 4; ++m)
#pragma unroll
            for (int n = 0; n < 4; ++n) {
                acc[m][n] = __builtin_amdgcn_mfma_f32_16x16x32_bf16(ah[m], bh[n], acc[m][n], 0, 0, 0);
                acc[m][n] = __builtin_amdgcn_mfma_f32_16x16x32_bf16(ah[m], bl[n], acc[m][n], 0, 0, 0);
                acc[m][n] = __builtin_amdgcn_mfma_f32_16x16x32_bf16(al[m], bh[n], acc[m][n], 0, 0, 0);
            }
    }

    const int rb = by * 128 + wr * 64 + kb * 4;
    const int cb = bx * 128 + wc * 64 + l15;
#pragma unroll
    for (int n = 0; n < 4; ++n) {
        int col = cb + n * 16;
        float bv = bias ? bias[col] : 0.0f;
#pragma unroll
        for (int m = 0; m < 4; ++m) {
            int row = rb + m * 16;
#pragma unroll
            for (int r = 0; r < 4; ++r)
                C[(size_t)(row + r) * N + col] = acc[m][n][r] + bv;
        }
    }
}

// ---------------------------------------------------------------------------
// dwconv+bn+pool+gelu (unchanged from R5 — XCD-local, verified fast).
// ---------------------------------------------------------------------------
__global__ __launch_bounds__(256, 4) void dwconv_bn_pool_gelu_kernel(
    const float* __restrict__ in, const float* __restrict__ wT,
    const float* __restrict__ scv, const float* __restrict__ shv,
    float* __restrict__ outg, float* __restrict__ pool)
{
    const int blk = blockIdx.x;
    const int xcd = blk & 7;
    const int j   = blk >> 3;
    const int b   = xcd + 8 * (j >> 6);
    const int g   = j & 63;
    const int gy  = g >> 3, gx = g & 7;
    const int tid = threadIdx.x;
    const int c4  = tid & 63;
    const int wv  = tid >> 6;
    const int c0  = c4 * 4;

    float4 wr[9];
#pragma unroll
    for (int t = 0; t < 9; ++t) wr[t] = *(const float4*)(wT + t * C_ + c0);
    const float4 sc = *(const float4*)(scv + c0);
    const float4 sh = *(const float4*)(shv + c0);

    const int x0 = gx * 7, y0 = gy * 7;
    const float* inb = in + (size_t)b * N_TOK * C_;
    float4 acc = make_float4(0, 0, 0, 0);

    for (int p = wv; p < 49; p += 4) {
        int py = p / 7, px = p - py * 7;
        int y = y0 + py, x = x0 + px;
        float cx = 0.f, cy = 0.f, cz = 0.f, cw = 0.f;
#pragma unroll
        for (int dy = -1; dy <= 1; ++dy) {
            int yy = y + dy;
            if (yy < 0 || yy >= H_IMG) continue;
#pragma unroll
            for (int dx = -1; dx <= 1; ++dx) {
                int xx = x + dx;
                if (xx < 0 || xx >= W_IMG) continue;
                const float4 iv = *(const float4*)(inb + (size_t)(yy * W_IMG + xx) * C_ + c0);
                const float4 w  = wr[(dy + 1) * 3 + (dx + 1)];
                cx = fmaf(iv.x, w.x, cx);
                cy = fmaf(iv.y, w.y, cy);
                cz = fmaf(iv.z, w.z, cz);
                cw = fmaf(iv.w, w.w, cw);
            }
        }
        float vx = cx * sc.x + sh.x;
        float vy = cy * sc.y + sh.y;
        float vz = cz * sc.z + sh.z;
        float vw = cw * sc.w + sh.w;
        acc.x += vx; acc.y += vy; acc.z += vz; acc.w += vw;
        *(float4*)(outg + ((size_t)b * N_TOK + y * W_IMG + x) * C_ + c0) =
            make_float4(geluf(vx), geluf(vy), geluf(vz), geluf(vw));
    }

    __shared__ float4 ps[4][64];
    ps[wv][c4] = acc;
    __syncthreads();
    if (tid < 64) {
        float4 s  = ps[0][tid];
        float4 t1 = ps[1][tid];
        float4 t2 = ps[2][tid];
        float4 t3 = ps[3][tid];
        const float r = 1.0f / 49.0f;
        *(float4*)(pool + ((size_t)b * 64 + g) * C_ + tid * 4) = make_float4(
            (s.x + t1.x + t2.x + t3.x) * r, (s.y + t1.y + t2.y + t3.y) * r,
            (s.z + t1.z + t2.z + t3.z) * r, (s.w + t1.w + t2.w + t3.w) * r);
    }
}

// ---------------------------------------------------------------------------
// dwconv3x3 + BN + add (unchanged from R5).
// ---------------------------------------------------------------------------
__global__ __launch_bounds__(256, 4) void dwconv_bn_add_kernel(
    const float* __restrict__ in, const float* __restrict__ wT,
    const float* __restrict__ scv, const float* __restrict__ shv,
    const float* __restrict__ add_, float* __restrict__ out)
{
    const int blk = blockIdx.x;
    const int xcd = blk & 7;
    const int j   = blk >> 3;
    const int b   = xcd + 8 * (j >> 6);
    const int g   = j & 63;
    const int gy  = g >> 3, gx = g & 7;
    const int tid = threadIdx.x;
    const int c4  = tid & 63;
    const int wv  = tid >> 6;
    const int c0  = c4 * 4;

    float4 wr[9];
#pragma unroll
    for (int t = 0; t < 9; ++t) wr[t] = *(const float4*)(wT + t * C_ + c0);
    const float4 sc = *(const float4*)(scv + c0);
    const float4 sh = *(const float4*)(shv + c0);

    const int x0 = gx * 7, y0 = gy * 7;
    const float* inb = in + (size_t)b * N_TOK * C_;

    for (int p = wv; p < 49; p += 4) {
        int py = p / 7, px = p - py * 7;
        int y = y0 + py, x = x0 + px;
        float cx = 0.f, cy = 0.f, cz = 0.f, cw = 0.f;
#pragma unroll
        for (int dy = -1; dy <= 1; ++dy) {
            int yy = y + dy;
            if (yy < 0 || yy >= H_IMG) continue;
#pragma unroll
            for (int dx = -1; dx <= 1; ++dx) {
                int xx = x + dx;
                if (xx < 0 || xx >= W_IMG) continue;
                const float4 iv = *(const float4*)(inb + (size_t)(yy * W_IMG + xx) * C_ + c0);
                const float4 w  = wr[(dy + 1) * 3 + (dx + 1)];
                cx = fmaf(iv.x, w.x, cx);
                cy = fmaf(iv.y, w.y, cy);
                cz = fmaf(iv.z, w.z, cz);
                cw = fmaf(iv.w, w.w, cw);
            }
        }
        size_t pix = (size_t)b * N_TOK + y * W_IMG + x;
        const float4 av = *(const float4*)(add_ + pix * C_ + c0);
        *(float4*)(out + pix * C_ + c0) = make_float4(
            cx * sc.x + sh.x + av.x, cy * sc.y + sh.y + av.y,
            cz * sc.z + sh.z + av.z, cw * sc.w + sh.w + av.w);
    }
}

// ---------------------------------------------------------------------------
// QK^T logits + per-row max (scaled). mrow_g[bh*64+i] = max_j attnL[bh][i][j].
// ---------------------------------------------------------------------------
__global__ __launch_bounds__(256) void qk_kernel(
    const float* __restrict__ q, const float* __restrict__ k,
    float* __restrict__ attnL, float* __restrict__ mrow_g)
{
    int bh = blockIdx.x;
    int b = bh >> 3, head = bh & 7;
    __shared__ float qs[64][33];
    __shared__ float ks[64][33];
    int tid = threadIdx.x;
    for (int t = tid; t < 512; t += 256) {
        int i = t >> 3, dq = (t & 7) * 4;
        const float4 qv = *(const float4*)(q + ((size_t)(b * 64 + i) * C_ + head * 32 + dq));
        const float4 kv = *(const float4*)(k + ((size_t)(b * 64 + i) * C_ + head * 32 + dq));
        qs[i][dq + 0] = qv.x; qs[i][dq + 1] = qv.y; qs[i][dq + 2] = qv.z; qs[i][dq + 3] = qv.w;
        ks[i][dq + 0] = kv.x; ks[i][dq + 1] = kv.y; ks[i][dq + 2] = kv.z; ks[i][dq + 3] = kv.w;
    }
    __syncthreads();
    int i  = tid >> 2;
    int jb = (tid & 3) * 16;
    float qr[32];
#pragma unroll
    for (int d = 0; d < 32; ++d) qr[d] = qs[i][d];
    float* outp = attnL + (size_t)bh * 4096 + i * 64 + jb;
    float mloc = -1e30f;
#pragma unroll
    for (int j = 0; j < 16; ++j) {
        float s = 0.f;
#pragma unroll
        for (int d = 0; d < 32; ++d) s = fmaf(qr[d], ks[jb + j][d], s);
        float sv = s * 0.0625f;          // C^-0.5
        outp[j] = sv;
        mloc = fmaxf(mloc, sv);
    }
    mloc = fmaxf(mloc, __shfl_xor(mloc, 1));
    mloc = fmaxf(mloc, __shfl_xor(mloc, 2));
    if ((tid & 3) == 0) mrow_g[bh * 64 + i] = mloc;
}

// ---------------------------------------------------------------------------
// Fused upsample(logits)->softmax-weights->PV via MFMA.
// Block = (b, head, chunk of 7 rows), XCD-aware. 256 thr / 4 waves.
// Per y: RY (y-lerped logits - rowmax) -> P[64i][56x] bf16 (each weight once)
// -> O += P·V via mfma_f32_16x16x32_bf16 (V split hi+lo, K=64 zero-pad).
// z kept fp32 per-thread, reduced in LDS. A-frag: row i stride 36dw; B-frag:
// Vq[d][x] rows (transposed at stage) -> b128 reads, 2-way bank alias (free).
// ---------------------------------------------------------------------------
#define S_ALS 0        // 64*28 f32 (3 grid rows of Al, 24 cols + pad)
#define S_P   1792     // 64 rows * 36 dw (64 bf16 + pad)
#define S_VH  4096     // 32 rows (d) * 36 dw (64 x-bf16 + pad)
#define S_VL  5248
#define S_RY  6400     // 64*12 f32
#define S_ZP  7168     // 64*4 f32
__global__ __launch_bounds__(256, 4) void attn_pv_kernel(
    const float* __restrict__ attnL,  // [BH][64][64]
    const float* __restrict__ mrow_g, // [BH][64]
    const float* __restrict__ v,      // [B][3136][256]
    float* __restrict__ part_o,       // [BH][NCH][64][32]
    float* __restrict__ part_z)       // [BH][NCH][64]
{
    __shared__ unsigned sm[7424];     // 29.7 KB
    float* smf = (float*)sm;

    const int blk   = blockIdx.x;
    const int xcd   = blk & 7;
    const int r8    = blk >> 3;               // 0..127
    const int b     = xcd + 8 * (r8 >> 6);
    const int rem   = r8 & 63;
    const int head  = rem >> 3;
    const int chunk = rem & 7;
    const int bh    = b * 8 + head;
    const int jb    = min(max(chunk - 1, 0), 5);   // Al grid-row window base

    const int tid  = threadIdx.x;
    const int lane = tid & 63;
    const int w    = tid >> 6;
    const int l15  = lane & 15, kb = lane >> 4;
    const int i    = tid >> 2;     // query row 0..63 (exp/RY mapping)
    const int dg   = tid & 3;      // x-quarter

    // ---- prologue: stage Als (24 cols), zero pads ----
    for (int u = tid; u < 384; u += 256) {
        int row = u / 6, cc = u % 6;
        float4 va = *(const float4*)(attnL + (size_t)bh * 4096 + row * 64 + jb * 8 + cc * 4);
        *(float4*)&smf[S_ALS + row * 28 + cc * 4] = va;
    }
    sm[S_P + (tid >> 2) * 36 + 28 + (tid & 3)] = 0;          // P x-pad 56..63
    {
        int base = (tid < 128) ? S_VH : S_VL;
        int q2 = tid & 127;
        sm[base + (q2 >> 2) * 36 + 28 + (q2 & 3)] = 0;       // Vq x2-pad 28..31
    }
    const float mr = mrow_g[bh * 64 + i];

    // per-thread x-interp coefficients (14 x's, unrolled -> registers)
    int   x0a[14]; float txa[14];
#pragma unroll
    for (int j = 0; j < 14; ++j) {
        int i0, i1; float t;
        up_coef(dg * 14 + j, i0, i1, t);
        x0a[j] = i0; txa[j] = t;
    }

    f32x4 acc[2];
    acc[0] = (f32x4)(0.0f); acc[1] = (f32x4)(0.0f);
    float zacc = 0.0f;

    for (int rr = 0; rr < 7; ++rr) {
        const int y = chunk * 7 + rr;
        __syncthreads();   // prev MFMA done; Als ready (first iter)

        // -- phase 1: stage V (transposed, split) + RY --
        float4 va, vb;
        if (tid < 224) {
            int x2 = tid >> 3, d0 = (tid & 7) * 4;
            const float* vp = v + ((size_t)b * N_TOK + y * W_IMG + 2 * x2) * C_ + head * 32 + d0;
            va = *(const float4*)vp;
            vb = *(const float4*)(vp + C_);
        }
        {
            int y0, y1; float ty;
            up_coef(y, y0, y1, ty);
#pragma unroll
            for (int kk2 = dg; kk2 < 9; kk2 += 4) {
                int ks2 = kk2 < 8 ? kk2 : 7;
                float a0 = smf[S_ALS + i * 28 + (y0 - jb) * 8 + ks2];
                float a1 = smf[S_ALS + i * 28 + (y1 - jb) * 8 + ks2];
                smf[S_RY + i * 12 + kk2] = fmaf(ty, a1 - a0, a0) - mr;
            }
        }
        if (tid < 224) {
            int x2 = tid >> 3, d0 = (tid & 7) * 4;
            float ae[4] = {va.x, va.y, va.z, va.w};
            float be[4] = {vb.x, vb.y, vb.z, vb.w};
#pragma unroll
            for (int j = 0; j < 4; ++j) {
                unsigned ua = __float_as_uint(ae[j]), ha = ua & 0xFFFF0000u;
                unsigned ub = __float_as_uint(be[j]), hb2 = ub & 0xFFFF0000u;
                sm[S_VH + (d0 + j) * 36 + x2] = (ha >> 16) | hb2;
                float la = ae[j] - __uint_as_float(ha);
                float lb = be[j] - __uint_as_float(hb2);
                sm[S_VL + (d0 + j) * 36 + x2] =
                    (__float_as_uint(la) >> 16) | (__float_as_uint(lb) & 0xFFFF0000u);
            }
        }
        __syncthreads();

        // -- phase 2: P = exp(lerp_x(RY)) -> bf16 LDS; z in fp32 --
#pragma unroll
        for (int j = 0; j < 7; ++j) {
            float r0 = smf[S_RY + i * 12 + x0a[2 * j]];
            float r1 = smf[S_RY + i * 12 + x0a[2 * j] + 1];
            float l0 = fmaf(txa[2 * j], r1 - r0, r0);
            float r2 = smf[S_RY + i * 12 + x0a[2 * j + 1]];
            float r3 = smf[S_RY + i * 12 + x0a[2 * j + 1] + 1];
            float l1 = fmaf(txa[2 * j + 1], r3 - r2, r2);
            float p0 = __expf(l0), p1 = __expf(l1);
            zacc += p0 + p1;
            sm[S_P + i * 36 + dg * 7 + j] = pack2_bf16(p0, p1);
        }
        __syncthreads();

        // -- phase 3: O += P·V (MFMA), wave w = i-rows w*16..+15 --
#pragma unroll
        for (int s = 0; s < 2; ++s) {
            bf16x8 pa = *(const bf16x8*)&sm[S_P + (w * 16 + l15) * 36 + s * 16 + kb * 4];
#pragma unroll
            for (int n = 0; n < 2; ++n) {
                bf16x8 bhv = *(const bf16x8*)&sm[S_VH + (n * 16 + l15) * 36 + s * 16 + kb * 4];
                bf16x8 blv = *(const bf16x8*)&sm[S_VL + (n * 16 + l15) * 36 + s * 16 + kb * 4];
                acc[n] = __builtin_amdgcn_mfma_f32_16x16x32_bf16(pa, bhv, acc[n], 0, 0, 0);
                acc[n] = __builtin_amdgcn_mfma_f32_16x16x32_bf16(pa, blv, acc[n], 0, 0, 0);
            }
        }
    }

    // ---- epilogue ----
    smf[S_ZP + i * 4 + dg] = zacc;
    __syncthreads();
    if (tid < 64) {
        float zt = smf[S_ZP + tid * 4] + smf[S_ZP + tid * 4 + 1] +
                   smf[S_ZP + tid * 4 + 2] + smf[S_ZP + tid * 4 + 3];
        part_z[((size_t)bh * NCH + chunk) * 64 + tid] = zt;
    }
    const int row4 = (lane >> 4) * 4;
#pragma unroll
    for (int n = 0; n < 2; ++n)
#pragma unroll
        for (int r2 = 0; r2 < 4; ++r2) {
            int i2 = w * 16 + row4 + r2;
            int d  = n * 16 + l15;
            part_o[(((size_t)bh * NCH + chunk) * 64 + i2) * 32 + d] = acc[n][r2];
        }
}

// ---------------------------------------------------------------------------
// Combine partials -> o_small [B][64][C], divide by Z.
// ---------------------------------------------------------------------------
__global__ __launch_bounds__(256) void combine_kernel(
    const float* __restrict__ part_o, const float* __restrict__ part_z,
    float* __restrict__ o_small)
{
    int idx = blockIdx.x * 256 + threadIdx.x;
    if (idx >= B_ * 64 * C_) return;
    int c = idx % C_;
    int g = (idx / C_) % 64;
    int b = idx / (C_ * 64);
    int head = c >> 5, d = c & 31;
    int bh = b * 8 + head;
    float oo = 0.f, zz = 0.f;
    for (int ch = 0; ch < NCH; ++ch) {
        oo += part_o[(((size_t)bh * NCH + ch) * 64 + g) * 32 + d];
        zz += part_z[((size_t)bh * NCH + ch) * 64 + g];
    }
    o_small[idx] = oo / zz;
}

// ---------------------------------------------------------------------------
// Bilinear upsample 8x8 -> 56x56, NHWC.
// ---------------------------------------------------------------------------
__global__ __launch_bounds__(256) void upsample7_kernel(
    const float* __restrict__ in, float* __restrict__ out)
{
    int idx = blockIdx.x * 256 + threadIdx.x;
    int c4  = idx % C4_;
    int pix = idx / C4_;
    int x = pix % W_IMG;
    int y = (pix / W_IMG) % H_IMG;
    int b = pix / (W_IMG * H_IMG);
    if (b >= B_) return;
    int y0, y1, x0, x1; float ty, tx;
    up_coef(y, y0, y1, ty);
    up_coef(x, x0, x1, tx);
    const float* base = in + (size_t)b * 64 * C_ + c4 * 4;
    const float4 v00 = *(const float4*)(base + (y0 * 8 + x0) * C_);
    const float4 v01 = *(const float4*)(base + (y0 * 8 + x1) * C_);
    const float4 v10 = *(const float4*)(base + (y1 * 8 + x0) * C_);
    const float4 v11 = *(const float4*)(base + (y1 * 8 + x1) * C_);
    float r0x = v00.x + tx * (v01.x - v00.x), r1x = v10.x + tx * (v11.x - v10.x);
    float r0y = v00.y + tx * (v01.y - v00.y), r1y = v10.y + tx * (v11.y - v10.y);
    float r0z = v00.z + tx * (v01.z - v00.z), r1z = v10.z + tx * (v11.z - v10.z);
    float r0w = v00.w + tx * (v01.w - v00.w), r1w = v10.w + tx * (v11.w - v10.w);
    *(float4*)(out + (size_t)idx * 4) = make_float4(
        r0x + ty * (r1x - r0x), r0y + ty * (r1y - r0y),
        r0z + ty * (r1z - r0z), r0w + ty * (r1w - r0w));
}

// ---------------------------------------------------------------------------
extern "C" void kernel_launch(void* const* d_in, const int* in_sizes, int n_in,
                              void* d_out, int out_size, void* d_ws, size_t ws_size,
                              hipStream_t stream)
{
    const float* x    = (const float*)d_in[0];
    const float* Wv   = (const float*)d_in[1];
    const float* c1w  = (const float*)d_in[2];
    const float* b1g  = (const float*)d_in[3];
    const float* b1b  = (const float*)d_in[4];
    const float* b1m  = (const float*)d_in[5];
    const float* b1v  = (const float*)d_in[6];
    const float* c2w  = (const float*)d_in[7];
    const float* b2g  = (const float*)d_in[8];
    const float* b2b  = (const float*)d_in[9];
    const float* b2m  = (const float*)d_in[10];
    const float* b2v  = (const float*)d_in[11];
    const float* vupw = (const float*)d_in[12];
    const float* b3g  = (const float*)d_in[13];
    const float* b3b  = (const float*)d_in[14];
    const float* b3m  = (const float*)d_in[15];
    const float* b3v  = (const float*)d_in[16];
    const float* Wp   = (const float*)d_in[17];
    const float* bp   = (const float*)d_in[18];
    float* out = (float*)d_out;
    float* ws  = (float*)d_ws;

    const size_t SZ = (size_t)B_ * N_TOK * C_;
    float* v       = ws;
    float* s1g     = v   + SZ;
    float* s2g     = s1g + SZ;
    float* q       = s2g + SZ;
    float* kk      = q  + (size_t)B_ * 64 * C_;
    float* attnL   = kk + (size_t)B_ * 64 * C_;
    float* part_o  = attnL  + (size_t)B_ * 8 * 64 * 64;
    float* part_z  = part_o + (size_t)B_ * 8 * NCH * 64 * 32;
    float* o_small = part_z + (size_t)B_ * 8 * NCH * 64;
    float* wT1     = o_small + (size_t)B_ * 64 * C_;
    float* wT2     = wT1 + 9 * C_;
    float* wT3     = wT2 + 9 * C_;
    float* sc1     = wT3 + 9 * C_;
    float* sh1     = sc1 + C_;
    float* sc2     = sh1 + C_;
    float* sh2     = sc2 + C_;
    float* sc3     = sh2 + C_;
    float* sh3     = sc3 + C_;
    float* mrow_g  = sh3 + C_;                  // B*8*64

    const int M = B_ * N_TOK;
    const int pix_blocks = B_ * N_TOK / 4;

    prep_kernel<<<1, 256, 0, stream>>>(c1w, c2w, vupw,
        b1g, b1b, b1m, b1v, b2g, b2b, b2m, b2v, b3g, b3b, b3m, b3v,
        wT1, wT2, wT3, sc1, sh1, sc2, sh2, sc3, sh3);
    gemm_nt_mfma_kernel<<<(M / 128) * (C_ / 128), 256, 0, stream>>>(x, Wv, nullptr, v, M, C_, C_);
    dwconv_bn_pool_gelu_kernel<<<1024, 256, 0, stream>>>(v, wT1, sc1, sh1, s1g, q);
    dwconv_bn_pool_gelu_kernel<<<1024, 256, 0, stream>>>(s1g, wT2, sc2, sh2, s2g, kk);
    qk_kernel<<<B_ * 8, 256, 0, stream>>>(q, kk, attnL, mrow_g);
    attn_pv_kernel<<<B_ * 8 * NCH, 256, 0, stream>>>(attnL, mrow_g, v, part_o, part_z);
    combine_kernel<<<B_ * 64 * C_ / 256, 256, 0, stream>>>(part_o, part_z, o_small);
    upsample7_kernel<<<pix_blocks, 256, 0, stream>>>(o_small, s1g);
    dwconv_bn_add_kernel<<<1024, 256, 0, stream>>>(s1g, wT3, sc3, sh3, s2g, v);
    gemm_nt_mfma_kernel<<<(M / 128) * (C_ / 128), 256, 0, stream>>>(v, Wp, bp, out, M, C_, C_);
}

// Round 7
// 231.831 us; speedup vs baseline: 1.6219x; 1.0918x over previous
//
#include <hip/hip_runtime.h>
#include <math.h>

// Problem constants (LocallyEnhancedAttention: B=16, N=3136, C=256, SR=7, HEADS=8)
#define B_     16
#define H_IMG  56
#define W_IMG  56
#define N_TOK  3136      // 56*56
#define C_     256
#define C4_    64        // C_/4
#define NHEAD  8
#define HDIM   32
#define NCH    8         // attn chunks (each = 7 image rows)

typedef float f32x4 __attribute__((ext_vector_type(4)));
typedef __bf16 bf16x8 __attribute__((ext_vector_type(8)));

__device__ __forceinline__ float geluf(float x) {
    return 0.5f * x * (1.0f + erff(x * 0.70710678118654752f));
}

// 8 -> 56 bilinear (half-pixel + edge renormalize == index clamp). f = (o-3)/7
__device__ __forceinline__ void up_coef(int o, int& i0, int& i1, float& t) {
    float f  = (float)(o - 3) * (1.0f / 7.0f);
    float fl = floorf(f);
    int   ii = (int)fl;
    t = f - fl;
    if (ii < 0)       { i0 = 0; i1 = 0; t = 0.0f; }
    else if (ii >= 7) { i0 = 7; i1 = 7; t = 0.0f; }
    else              { i0 = ii; i1 = ii + 1; }
}

__device__ __forceinline__ void split_bf16(float4 f, uint2& hi, uint2& lo) {
    unsigned u0 = __float_as_uint(f.x), u1 = __float_as_uint(f.y);
    unsigned u2 = __float_as_uint(f.z), u3 = __float_as_uint(f.w);
    unsigned h0 = u0 & 0xFFFF0000u, h1 = u1 & 0xFFFF0000u;
    unsigned h2 = u2 & 0xFFFF0000u, h3 = u3 & 0xFFFF0000u;
    hi = make_uint2((h0 >> 16) | h1, (h2 >> 16) | h3);
    float l0 = f.x - __uint_as_float(h0);
    float l1 = f.y - __uint_as_float(h1);
    float l2 = f.z - __uint_as_float(h2);
    float l3 = f.w - __uint_as_float(h3);
    lo = make_uint2((__float_as_uint(l0) >> 16) | (__float_as_uint(l1) & 0xFFFF0000u),
                    (__float_as_uint(l2) >> 16) | (__float_as_uint(l3) & 0xFFFF0000u));
}

__device__ __forceinline__ unsigned pack2_bf16(float a, float b) {
    __bf16 ha = (__bf16)a, hb = (__bf16)b;
    unsigned short ua = __builtin_bit_cast(unsigned short, ha);
    unsigned short ub = __builtin_bit_cast(unsigned short, hb);
    return (unsigned)ua | ((unsigned)ub << 16);
}

// ---------------------------------------------------------------------------
// Prep: transpose dw weights [C][9] -> [9][C]; fold BN into scale/shift.
// ---------------------------------------------------------------------------
__global__ void prep_kernel(
    const float* __restrict__ w1, const float* __restrict__ w2, const float* __restrict__ w3,
    const float* __restrict__ g1, const float* __restrict__ b1, const float* __restrict__ m1, const float* __restrict__ v1,
    const float* __restrict__ g2, const float* __restrict__ b2, const float* __restrict__ m2, const float* __restrict__ v2,
    const float* __restrict__ g3, const float* __restrict__ b3, const float* __restrict__ m3, const float* __restrict__ v3,
    float* __restrict__ wT1, float* __restrict__ wT2, float* __restrict__ wT3,
    float* __restrict__ sc1, float* __restrict__ sh1,
    float* __restrict__ sc2, float* __restrict__ sh2,
    float* __restrict__ sc3, float* __restrict__ sh3)
{
    int c = threadIdx.x;
#pragma unroll
    for (int t = 0; t < 9; ++t) {
        wT1[t * C_ + c] = w1[c * 9 + t];
        wT2[t * C_ + c] = w2[c * 9 + t];
        wT3[t * C_ + c] = w3[c * 9 + t];
    }
    float s1 = g1[c] * rsqrtf(v1[c] + 1e-5f); sc1[c] = s1; sh1[c] = b1[c] - m1[c] * s1;
    float s2 = g2[c] * rsqrtf(v2[c] + 1e-5f); sc2[c] = s2; sh2[c] = b2[c] - m2[c] * s2;
    float s3 = g3[c] * rsqrtf(v3[c] + 1e-5f); sc3[c] = s3; sh3[c] = b3[c] - m3[c] * s3;
}

// ---------------------------------------------------------------------------
// MFMA GEMM (NT), split-bf16, K=256 hardcoded, fully unrolled with register
// prefetch: iter k's global loads are issued during iter k-1's MFMA section.
// ---------------------------------------------------------------------------
#define AHI 0
#define ALO 2560
#define BHI 5120
#define BLO 7680
__global__ __launch_bounds__(256, 2) void gemm_nt_mfma_kernel(
    const float* __restrict__ A,    // [M][256]
    const float* __restrict__ Bm,   // [N][256]
    const float* __restrict__ bias, // [N] or nullptr
    float* __restrict__ C,          // [M][N]
    int M, int N)
{
    __shared__ unsigned lds[10240];
    const int tid  = threadIdx.x;
    const int nb   = N >> 7;
    const int bx   = blockIdx.x % nb;
    const int by   = blockIdx.x / nb;
    const int lane = tid & 63;
    const int wv   = tid >> 6;
    const int wr   = wv >> 1, wc = wv & 1;
    const int l15  = lane & 15, kb = lane >> 4;

    const int srow = tid >> 1;
    const int sdw  = (tid & 1) * 8;
    const float* Ap = A  + (size_t)(by * 128 + srow) * 256 + (tid & 1) * 16;
    const float* Bp = Bm + (size_t)(bx * 128 + srow) * 256 + (tid & 1) * 16;

    f32x4 acc[4][4];
#pragma unroll
    for (int m = 0; m < 4; ++m)
#pragma unroll
        for (int n = 0; n < 4; ++n) acc[m][n] = (f32x4)(0.0f);

    float4 a[4], b[4];
#pragma unroll
    for (int i = 0; i < 4; ++i) { a[i] = *(const float4*)(Ap + i * 4); }
#pragma unroll
    for (int i = 0; i < 4; ++i) { b[i] = *(const float4*)(Bp + i * 4); }

#pragma unroll
    for (int k0 = 0; k0 < 256; k0 += 32) {
        __syncthreads();
        {
            uint2 h[4], l[4];
#pragma unroll
            for (int i = 0; i < 4; ++i) split_bf16(a[i], h[i], l[i]);
            *(uint4*)&lds[AHI + srow * 20 + sdw]     = make_uint4(h[0].x, h[0].y, h[1].x, h[1].y);
            *(uint4*)&lds[AHI + srow * 20 + sdw + 4] = make_uint4(h[2].x, h[2].y, h[3].x, h[3].y);
            *(uint4*)&lds[ALO + srow * 20 + sdw]     = make_uint4(l[0].x, l[0].y, l[1].x, l[1].y);
            *(uint4*)&lds[ALO + srow * 20 + sdw + 4] = make_uint4(l[2].x, l[2].y, l[3].x, l[3].y);
#pragma unroll
            for (int i = 0; i < 4; ++i) split_bf16(b[i], h[i], l[i]);
            *(uint4*)&lds[BHI + srow * 20 + sdw]     = make_uint4(h[0].x, h[0].y, h[1].x, h[1].y);
            *(uint4*)&lds[BHI + srow * 20 + sdw + 4] = make_uint4(h[2].x, h[2].y, h[3].x, h[3].y);
            *(uint4*)&lds[BLO + srow * 20 + sdw]     = make_uint4(l[0].x, l[0].y, l[1].x, l[1].y);
            *(uint4*)&lds[BLO + srow * 20 + sdw + 4] = make_uint4(l[2].x, l[2].y, l[3].x, l[3].y);
        }
        // prefetch next K-slab (registers free after the stores above)
        if (k0 + 32 < 256) {
#pragma unroll
            for (int i = 0; i < 4; ++i) a[i] = *(const float4*)(Ap + k0 + 32 + i * 4);
#pragma unroll
            for (int i = 0; i < 4; ++i) b[i] = *(const float4*)(Bp + k0 + 32 + i * 4);
        }
        __syncthreads();

        bf16x8 ah[4], al[4], bh[4], bl[4];
#pragma unroll
        for (int m = 0; m < 4; ++m) {
            int r = wr * 64 + m * 16 + l15;
            ah[m] = *(const bf16x8*)&lds[AHI + r * 20 + kb * 4];
            al[m] = *(const bf16x8*)&lds[ALO + r * 20 + kb * 4];
        }
#pragma unroll
        for (int n = 0; n < 4; ++n) {
            int r = wc * 64 + n * 16 + l15;
            bh[n] = *(const bf16x8*)&lds[BHI + r * 20 + kb * 4];
            bl[n] = *(const bf16x8*)&lds[BLO + r * 20 + kb * 4];
        }
#pragma unroll
        for (int m = 0; m < 4; ++m)
#pragma unroll
            for (int n = 0; n < 4; ++n) {
                acc[m][n] = __builtin_amdgcn_mfma_f32_16x16x32_bf16(ah[m], bh[n], acc[m][n], 0, 0, 0);
                acc[m][n] = __builtin_amdgcn_mfma_f32_16x16x32_bf16(ah[m], bl[n], acc[m][n], 0, 0, 0);
                acc[m][n] = __builtin_amdgcn_mfma_f32_16x16x32_bf16(al[m], bh[n], acc[m][n], 0, 0, 0);
            }
    }

    const int rb = by * 128 + wr * 64 + kb * 4;
    const int cb = bx * 128 + wc * 64 + l15;
#pragma unroll
    for (int n = 0; n < 4; ++n) {
        int col = cb + n * 16;
        float bv = bias ? bias[col] : 0.0f;
#pragma unroll
        for (int m = 0; m < 4; ++m) {
            int row = rb + m * 16;
#pragma unroll
            for (int r = 0; r < 4; ++r)
                C[(size_t)(row + r) * N + col] = acc[m][n][r] + bv;
        }
    }
}

// ---------------------------------------------------------------------------
// dwconv+bn+pool+gelu (unchanged from R5 — XCD-local, verified fast).
// ---------------------------------------------------------------------------
__global__ __launch_bounds__(256, 4) void dwconv_bn_pool_gelu_kernel(
    const float* __restrict__ in, const float* __restrict__ wT,
    const float* __restrict__ scv, const float* __restrict__ shv,
    float* __restrict__ outg, float* __restrict__ pool)
{
    const int blk = blockIdx.x;
    const int xcd = blk & 7;
    const int j   = blk >> 3;
    const int b   = xcd + 8 * (j >> 6);
    const int g   = j & 63;
    const int gy  = g >> 3, gx = g & 7;
    const int tid = threadIdx.x;
    const int c4  = tid & 63;
    const int wv  = tid >> 6;
    const int c0  = c4 * 4;

    float4 wr[9];
#pragma unroll
    for (int t = 0; t < 9; ++t) wr[t] = *(const float4*)(wT + t * C_ + c0);
    const float4 sc = *(const float4*)(scv + c0);
    const float4 sh = *(const float4*)(shv + c0);

    const int x0 = gx * 7, y0 = gy * 7;
    const float* inb = in + (size_t)b * N_TOK * C_;
    float4 acc = make_float4(0, 0, 0, 0);

    for (int p = wv; p < 49; p += 4) {
        int py = p / 7, px = p - py * 7;
        int y = y0 + py, x = x0 + px;
        float cx = 0.f, cy = 0.f, cz = 0.f, cw = 0.f;
#pragma unroll
        for (int dy = -1; dy <= 1; ++dy) {
            int yy = y + dy;
            if (yy < 0 || yy >= H_IMG) continue;
#pragma unroll
            for (int dx = -1; dx <= 1; ++dx) {
                int xx = x + dx;
                if (xx < 0 || xx >= W_IMG) continue;
                const float4 iv = *(const float4*)(inb + (size_t)(yy * W_IMG + xx) * C_ + c0);
                const float4 w  = wr[(dy + 1) * 3 + (dx + 1)];
                cx = fmaf(iv.x, w.x, cx);
                cy = fmaf(iv.y, w.y, cy);
                cz = fmaf(iv.z, w.z, cz);
                cw = fmaf(iv.w, w.w, cw);
            }
        }
        float vx = cx * sc.x + sh.x;
        float vy = cy * sc.y + sh.y;
        float vz = cz * sc.z + sh.z;
        float vw = cw * sc.w + sh.w;
        acc.x += vx; acc.y += vy; acc.z += vz; acc.w += vw;
        *(float4*)(outg + ((size_t)b * N_TOK + y * W_IMG + x) * C_ + c0) =
            make_float4(geluf(vx), geluf(vy), geluf(vz), geluf(vw));
    }

    __shared__ float4 ps[4][64];
    ps[wv][c4] = acc;
    __syncthreads();
    if (tid < 64) {
        float4 s  = ps[0][tid];
        float4 t1 = ps[1][tid];
        float4 t2 = ps[2][tid];
        float4 t3 = ps[3][tid];
        const float r = 1.0f / 49.0f;
        *(float4*)(pool + ((size_t)b * 64 + g) * C_ + tid * 4) = make_float4(
            (s.x + t1.x + t2.x + t3.x) * r, (s.y + t1.y + t2.y + t3.y) * r,
            (s.z + t1.z + t2.z + t3.z) * r, (s.w + t1.w + t2.w + t3.w) * r);
    }
}

// ---------------------------------------------------------------------------
// FUSED: conv3x3(bilinear_up(o_small)) + BN + add. The upsample intermediate
// is never materialized: each conv tap is bilerped on the fly from o_small
// (256 KB, L1/L2-resident). 3 fine rows -> <=3 coarse rows (monotone y0),
// so per dy we load 2 coarse rows x 3 cols, y-lerp in registers, x-lerp via
// branchless select (no runtime-indexed register arrays).
// ---------------------------------------------------------------------------
__global__ __launch_bounds__(256, 4) void dwconv_up_bn_add_kernel(
    const float* __restrict__ osm,    // [B][8][8][C]
    const float* __restrict__ wT,     // [9][C]
    const float* __restrict__ scv, const float* __restrict__ shv,
    const float* __restrict__ add_,   // [B][56][56][C]
    float* __restrict__ out)
{
    const int blk = blockIdx.x;
    const int xcd = blk & 7;
    const int j   = blk >> 3;
    const int b   = xcd + 8 * (j >> 6);
    const int g   = j & 63;
    const int gy  = g >> 3, gx = g & 7;
    const int tid = threadIdx.x;
    const int c4  = tid & 63;
    const int wv  = tid >> 6;
    const int c0  = c4 * 4;

    float4 wr[9];
#pragma unroll
    for (int t = 0; t < 9; ++t) wr[t] = *(const float4*)(wT + t * C_ + c0);
    const float4 sc = *(const float4*)(scv + c0);
    const float4 sh = *(const float4*)(shv + c0);

    const float* ob = osm + (size_t)b * 64 * C_ + c0;

    for (int p = wv; p < 49; p += 4) {
        int py = p / 7, px = p - py * 7;
        int y = gy * 7 + py, x = gx * 7 + px;

        // x-direction coefficients for the 3 conv columns
        int   xc0 = 0, xcs[3]; float txs[3]; bool xv[3];
        {
            bool first = true;
#pragma unroll
            for (int d = 0; d < 3; ++d) {
                int xx = x + d - 1;
                xv[d] = (xx >= 0 && xx < W_IMG);
                if (xv[d]) {
                    int i0, i1; float t;
                    up_coef(xx, i0, i1, t);
                    xcs[d] = i0; txs[d] = t;
                    if (first) { xc0 = i0; first = false; }
                } else { xcs[d] = 0; txs[d] = 0.f; }
            }
        }
        const int cA = min(xc0, 7), cB = min(xc0 + 1, 7), cC = min(xc0 + 2, 7);

        float ax = 0.f, ay = 0.f, az = 0.f, aw = 0.f;
#pragma unroll
        for (int d = 0; d < 3; ++d) {
            int yy = y + d - 1;
            if (yy < 0 || yy >= H_IMG) continue;
            int y0, y1; float ty;
            up_coef(yy, y0, y1, ty);
            const float* r0p = ob + (size_t)(y0 * 8) * C_;
            const float* r1p = ob + (size_t)(y1 * 8) * C_;
            // y-lerped coarse cols (registers, named — no runtime indexing)
            float4 ra0 = *(const float4*)(r0p + cA * C_);
            float4 ra1 = *(const float4*)(r1p + cA * C_);
            float4 rb0 = *(const float4*)(r0p + cB * C_);
            float4 rb1 = *(const float4*)(r1p + cB * C_);
            float4 rc0 = *(const float4*)(r0p + cC * C_);
            float4 rc1 = *(const float4*)(r1p + cC * C_);
            float RAx = fmaf(ty, ra1.x - ra0.x, ra0.x), RAy = fmaf(ty, ra1.y - ra0.y, ra0.y);
            float RAz = fmaf(ty, ra1.z - ra0.z, ra0.z), RAw = fmaf(ty, ra1.w - ra0.w, ra0.w);
            float RBx = fmaf(ty, rb1.x - rb0.x, rb0.x), RBy = fmaf(ty, rb1.y - rb0.y, rb0.y);
            float RBz = fmaf(ty, rb1.z - rb0.z, rb0.z), RBw = fmaf(ty, rb1.w - rb0.w, rb0.w);
            float RCx = fmaf(ty, rc1.x - rc0.x, rc0.x), RCy = fmaf(ty, rc1.y - rc0.y, rc0.y);
            float RCz = fmaf(ty, rc1.z - rc0.z, rc0.z), RCw = fmaf(ty, rc1.w - rc0.w, rc0.w);
#pragma unroll
            for (int e = 0; e < 3; ++e) {
                if (!xv[e]) continue;
                bool hi2 = (xcs[e] != xc0);           // x-pair select: (A,B) or (B,C)
                float lox = hi2 ? RBx : RAx, loy = hi2 ? RBy : RAy;
                float loz = hi2 ? RBz : RAz, low = hi2 ? RBw : RAw;
                float hix = hi2 ? RCx : RBx, hiy = hi2 ? RCy : RBy;
                float hiz = hi2 ? RCz : RBz, hiw = hi2 ? RCw : RBw;
                float tx = txs[e];
                float vx2 = fmaf(tx, hix - lox, lox);
                float vy2 = fmaf(tx, hiy - loy, loy);
                float vz2 = fmaf(tx, hiz - loz, loz);
                float vw2 = fmaf(tx, hiw - low, low);
                const float4 w = wr[d * 3 + e];
                ax = fmaf(vx2, w.x, ax);
                ay = fmaf(vy2, w.y, ay);
                az = fmaf(vz2, w.z, az);
                aw = fmaf(vw2, w.w, aw);
            }
        }
        size_t pix = (size_t)b * N_TOK + y * W_IMG + x;
        const float4 av = *(const float4*)(add_ + pix * C_ + c0);
        *(float4*)(out + pix * C_ + c0) = make_float4(
            ax * sc.x + sh.x + av.x, ay * sc.y + sh.y + av.y,
            az * sc.z + sh.z + av.z, aw * sc.w + sh.w + av.w);
    }
}

// ---------------------------------------------------------------------------
// QK^T logits + per-row max (scaled).
// ---------------------------------------------------------------------------
__global__ __launch_bounds__(256) void qk_kernel(
    const float* __restrict__ q, const float* __restrict__ k,
    float* __restrict__ attnL, float* __restrict__ mrow_g)
{
    int bh = blockIdx.x;
    int b = bh >> 3, head = bh & 7;
    __shared__ float qs[64][33];
    __shared__ float ks[64][33];
    int tid = threadIdx.x;
    for (int t = tid; t < 512; t += 256) {
        int i = t >> 3, dq = (t & 7) * 4;
        const float4 qv = *(const float4*)(q + ((size_t)(b * 64 + i) * C_ + head * 32 + dq));
        const float4 kv = *(const float4*)(k + ((size_t)(b * 64 + i) * C_ + head * 32 + dq));
        qs[i][dq + 0] = qv.x; qs[i][dq + 1] = qv.y; qs[i][dq + 2] = qv.z; qs[i][dq + 3] = qv.w;
        ks[i][dq + 0] = kv.x; ks[i][dq + 1] = kv.y; ks[i][dq + 2] = kv.z; ks[i][dq + 3] = kv.w;
    }
    __syncthreads();
    int i  = tid >> 2;
    int jb = (tid & 3) * 16;
    float qr[32];
#pragma unroll
    for (int d = 0; d < 32; ++d) qr[d] = qs[i][d];
    float* outp = attnL + (size_t)bh * 4096 + i * 64 + jb;
    float mloc = -1e30f;
#pragma unroll
    for (int j = 0; j < 16; ++j) {
        float s = 0.f;
#pragma unroll
        for (int d = 0; d < 32; ++d) s = fmaf(qr[d], ks[jb + j][d], s);
        float sv = s * 0.0625f;          // C^-0.5
        outp[j] = sv;
        mloc = fmaxf(mloc, sv);
    }
    mloc = fmaxf(mloc, __shfl_xor(mloc, 1));
    mloc = fmaxf(mloc, __shfl_xor(mloc, 2));
    if ((tid & 3) == 0) mrow_g[bh * 64 + i] = mloc;
}

// ---------------------------------------------------------------------------
// Fused upsample(logits)->softmax-weights->PV via MFMA (unchanged from R6).
// ---------------------------------------------------------------------------
#define S_ALS 0
#define S_P   1792
#define S_VH  4096
#define S_VL  5248
#define S_RY  6400
#define S_ZP  7168
__global__ __launch_bounds__(256, 4) void attn_pv_kernel(
    const float* __restrict__ attnL,
    const float* __restrict__ mrow_g,
    const float* __restrict__ v,
    float* __restrict__ part_o,
    float* __restrict__ part_z)
{
    __shared__ unsigned sm[7424];
    float* smf = (float*)sm;

    const int blk   = blockIdx.x;
    const int xcd   = blk & 7;
    const int r8    = blk >> 3;
    const int b     = xcd + 8 * (r8 >> 6);
    const int rem   = r8 & 63;
    const int head  = rem >> 3;
    const int chunk = rem & 7;
    const int bh    = b * 8 + head;
    const int jb    = min(max(chunk - 1, 0), 5);

    const int tid  = threadIdx.x;
    const int lane = tid & 63;
    const int w    = tid >> 6;
    const int l15  = lane & 15, kb = lane >> 4;
    const int i    = tid >> 2;
    const int dg   = tid & 3;

    for (int u = tid; u < 384; u += 256) {
        int row = u / 6, cc = u % 6;
        float4 va = *(const float4*)(attnL + (size_t)bh * 4096 + row * 64 + jb * 8 + cc * 4);
        *(float4*)&smf[S_ALS + row * 28 + cc * 4] = va;
    }
    sm[S_P + (tid >> 2) * 36 + 28 + (tid & 3)] = 0;
    {
        int base = (tid < 128) ? S_VH : S_VL;
        int q2 = tid & 127;
        sm[base + (q2 >> 2) * 36 + 28 + (q2 & 3)] = 0;
    }
    const float mr = mrow_g[bh * 64 + i];

    int   x0a[14]; float txa[14];
#pragma unroll
    for (int j = 0; j < 14; ++j) {
        int i0, i1; float t;
        up_coef(dg * 14 + j, i0, i1, t);
        x0a[j] = i0; txa[j] = t;
    }

    f32x4 acc[2];
    acc[0] = (f32x4)(0.0f); acc[1] = (f32x4)(0.0f);
    float zacc = 0.0f;

    for (int rr = 0; rr < 7; ++rr) {
        const int y = chunk * 7 + rr;
        __syncthreads();

        float4 va, vb;
        if (tid < 224) {
            int x2 = tid >> 3, d0 = (tid & 7) * 4;
            const float* vp = v + ((size_t)b * N_TOK + y * W_IMG + 2 * x2) * C_ + head * 32 + d0;
            va = *(const float4*)vp;
            vb = *(const float4*)(vp + C_);
        }
        {
            int y0, y1; float ty;
            up_coef(y, y0, y1, ty);
#pragma unroll
            for (int kk2 = dg; kk2 < 9; kk2 += 4) {
                int ks2 = kk2 < 8 ? kk2 : 7;
                float a0 = smf[S_ALS + i * 28 + (y0 - jb) * 8 + ks2];
                float a1 = smf[S_ALS + i * 28 + (y1 - jb) * 8 + ks2];
                smf[S_RY + i * 12 + kk2] = fmaf(ty, a1 - a0, a0) - mr;
            }
        }
        if (tid < 224) {
            int x2 = tid >> 3, d0 = (tid & 7) * 4;
            float ae[4] = {va.x, va.y, va.z, va.w};
            float be[4] = {vb.x, vb.y, vb.z, vb.w};
#pragma unroll
            for (int j = 0; j < 4; ++j) {
                unsigned ua = __float_as_uint(ae[j]), ha = ua & 0xFFFF0000u;
                unsigned ub = __float_as_uint(be[j]), hb2 = ub & 0xFFFF0000u;
                sm[S_VH + (d0 + j) * 36 + x2] = (ha >> 16) | hb2;
                float la = ae[j] - __uint_as_float(ha);
                float lb = be[j] - __uint_as_float(hb2);
                sm[S_VL + (d0 + j) * 36 + x2] =
                    (__float_as_uint(la) >> 16) | (__float_as_uint(lb) & 0xFFFF0000u);
            }
        }
        __syncthreads();

#pragma unroll
        for (int j = 0; j < 7; ++j) {
            float r0 = smf[S_RY + i * 12 + x0a[2 * j]];
            float r1 = smf[S_RY + i * 12 + x0a[2 * j] + 1];
            float l0 = fmaf(txa[2 * j], r1 - r0, r0);
            float r2 = smf[S_RY + i * 12 + x0a[2 * j + 1]];
            float r3 = smf[S_RY + i * 12 + x0a[2 * j + 1] + 1];
            float l1 = fmaf(txa[2 * j + 1], r3 - r2, r2);
            float p0 = __expf(l0), p1 = __expf(l1);
            zacc += p0 + p1;
            sm[S_P + i * 36 + dg * 7 + j] = pack2_bf16(p0, p1);
        }
        __syncthreads();

#pragma unroll
        for (int s = 0; s < 2; ++s) {
            bf16x8 pa = *(const bf16x8*)&sm[S_P + (w * 16 + l15) * 36 + s * 16 + kb * 4];
#pragma unroll
            for (int n = 0; n < 2; ++n) {
                bf16x8 bhv = *(const bf16x8*)&sm[S_VH + (n * 16 + l15) * 36 + s * 16 + kb * 4];
                bf16x8 blv = *(const bf16x8*)&sm[S_VL + (n * 16 + l15) * 36 + s * 16 + kb * 4];
                acc[n] = __builtin_amdgcn_mfma_f32_16x16x32_bf16(pa, bhv, acc[n], 0, 0, 0);
                acc[n] = __builtin_amdgcn_mfma_f32_16x16x32_bf16(pa, blv, acc[n], 0, 0, 0);
            }
        }
    }

    smf[S_ZP + i * 4 + dg] = zacc;
    __syncthreads();
    if (tid < 64) {
        float zt = smf[S_ZP + tid * 4] + smf[S_ZP + tid * 4 + 1] +
                   smf[S_ZP + tid * 4 + 2] + smf[S_ZP + tid * 4 + 3];
        part_z[((size_t)bh * NCH + chunk) * 64 + tid] = zt;
    }
    const int row4 = (lane >> 4) * 4;
#pragma unroll
    for (int n = 0; n < 2; ++n)
#pragma unroll
        for (int r2 = 0; r2 < 4; ++r2) {
            int i2 = w * 16 + row4 + r2;
            int d  = n * 16 + l15;
            part_o[(((size_t)bh * NCH + chunk) * 64 + i2) * 32 + d] = acc[n][r2];
        }
}

// ---------------------------------------------------------------------------
// Combine partials -> o_small [B][64][C], divide by Z.
// ---------------------------------------------------------------------------
__global__ __launch_bounds__(256) void combine_kernel(
    const float* __restrict__ part_o, const float* __restrict__ part_z,
    float* __restrict__ o_small)
{
    int idx = blockIdx.x * 256 + threadIdx.x;
    if (idx >= B_ * 64 * C_) return;
    int c = idx % C_;
    int g = (idx / C_) % 64;
    int b = idx / (C_ * 64);
    int head = c >> 5, d = c & 31;
    int bh = b * 8 + head;
    float oo = 0.f, zz = 0.f;
    for (int ch = 0; ch < NCH; ++ch) {
        oo += part_o[(((size_t)bh * NCH + ch) * 64 + g) * 32 + d];
        zz += part_z[((size_t)bh * NCH + ch) * 64 + g];
    }
    o_small[idx] = oo / zz;
}

// ---------------------------------------------------------------------------
extern "C" void kernel_launch(void* const* d_in, const int* in_sizes, int n_in,
                              void* d_out, int out_size, void* d_ws, size_t ws_size,
                              hipStream_t stream)
{
    const float* x    = (const float*)d_in[0];
    const float* Wv   = (const float*)d_in[1];
    const float* c1w  = (const float*)d_in[2];
    const float* b1g  = (const float*)d_in[3];
    const float* b1b  = (const float*)d_in[4];
    const float* b1m  = (const float*)d_in[5];
    const float* b1v  = (const float*)d_in[6];
    const float* c2w  = (const float*)d_in[7];
    const float* b2g  = (const float*)d_in[8];
    const float* b2b  = (const float*)d_in[9];
    const float* b2m  = (const float*)d_in[10];
    const float* b2v  = (const float*)d_in[11];
    const float* vupw = (const float*)d_in[12];
    const float* b3g  = (const float*)d_in[13];
    const float* b3b  = (const float*)d_in[14];
    const float* b3m  = (const float*)d_in[15];
    const float* b3v  = (const float*)d_in[16];
    const float* Wp   = (const float*)d_in[17];
    const float* bp   = (const float*)d_in[18];
    float* out = (float*)d_out;
    float* ws  = (float*)d_ws;

    const size_t SZ = (size_t)B_ * N_TOK * C_;
    float* v       = ws;
    float* s1g     = v   + SZ;
    float* s2g     = s1g + SZ;
    float* q       = s2g + SZ;
    float* kk      = q  + (size_t)B_ * 64 * C_;
    float* attnL   = kk + (size_t)B_ * 64 * C_;
    float* part_o  = attnL  + (size_t)B_ * 8 * 64 * 64;
    float* part_z  = part_o + (size_t)B_ * 8 * NCH * 64 * 32;
    float* o_small = part_z + (size_t)B_ * 8 * NCH * 64;
    float* wT1     = o_small + (size_t)B_ * 64 * C_;
    float* wT2     = wT1 + 9 * C_;
    float* wT3     = wT2 + 9 * C_;
    float* sc1     = wT3 + 9 * C_;
    float* sh1     = sc1 + C_;
    float* sc2     = sh1 + C_;
    float* sh2     = sc2 + C_;
    float* sc3     = sh2 + C_;
    float* sh3     = sc3 + C_;
    float* mrow_g  = sh3 + C_;

    const int M = B_ * N_TOK;

    prep_kernel<<<1, 256, 0, stream>>>(c1w, c2w, vupw,
        b1g, b1b, b1m, b1v, b2g, b2b, b2m, b2v, b3g, b3b, b3m, b3v,
        wT1, wT2, wT3, sc1, sh1, sc2, sh2, sc3, sh3);
    gemm_nt_mfma_kernel<<<(M / 128) * (C_ / 128), 256, 0, stream>>>(x, Wv, nullptr, v, M, C_);
    dwconv_bn_pool_gelu_kernel<<<1024, 256, 0, stream>>>(v, wT1, sc1, sh1, s1g, q);
    dwconv_bn_pool_gelu_kernel<<<1024, 256, 0, stream>>>(s1g, wT2, sc2, sh2, s2g, kk);
    qk_kernel<<<B_ * 8, 256, 0, stream>>>(q, kk, attnL, mrow_g);
    attn_pv_kernel<<<B_ * 8 * NCH, 256, 0, stream>>>(attnL, mrow_g, v, part_o, part_z);
    combine_kernel<<<B_ * 64 * C_ / 256, 256, 0, stream>>>(part_o, part_z, o_small);
    // conv3 with fused on-the-fly bilinear upsample (no 51 MB intermediate)
    dwconv_up_bn_add_kernel<<<1024, 256, 0, stream>>>(o_small, wT3, sc3, sh3, s2g, v);
    gemm_nt_mfma_kernel<<<(M / 128) * (C_ / 128), 256, 0, stream>>>(v, Wp, bp, out, M, C_);
}

// Round 8
// 212.061 us; speedup vs baseline: 1.7731x; 1.0932x over previous
//
#include <hip/hip_runtime.h>
#include <math.h>

// Problem constants (LocallyEnhancedAttention: B=16, N=3136, C=256, SR=7, HEADS=8)
#define B_     16
#define H_IMG  56
#define W_IMG  56
#define N_TOK  3136      // 56*56
#define C_     256
#define C4_    64        // C_/4
#define NHEAD  8
#define HDIM   32
#define NCH    8         // attn chunks (each = 7 image rows)

typedef float f32x4 __attribute__((ext_vector_type(4)));
typedef __bf16 bf16x8 __attribute__((ext_vector_type(8)));

__device__ __forceinline__ float geluf(float x) {
    return 0.5f * x * (1.0f + erff(x * 0.70710678118654752f));
}

// 8 -> 56 bilinear (half-pixel + edge renormalize == index clamp). f = (o-3)/7
__device__ __forceinline__ void up_coef(int o, int& i0, int& i1, float& t) {
    float f  = (float)(o - 3) * (1.0f / 7.0f);
    float fl = floorf(f);
    int   ii = (int)fl;
    t = f - fl;
    if (ii < 0)       { i0 = 0; i1 = 0; t = 0.0f; }
    else if (ii >= 7) { i0 = 7; i1 = 7; t = 0.0f; }
    else              { i0 = ii; i1 = ii + 1; }
}

__device__ __forceinline__ void split_bf16(float4 f, uint2& hi, uint2& lo) {
    unsigned u0 = __float_as_uint(f.x), u1 = __float_as_uint(f.y);
    unsigned u2 = __float_as_uint(f.z), u3 = __float_as_uint(f.w);
    unsigned h0 = u0 & 0xFFFF0000u, h1 = u1 & 0xFFFF0000u;
    unsigned h2 = u2 & 0xFFFF0000u, h3 = u3 & 0xFFFF0000u;
    hi = make_uint2((h0 >> 16) | h1, (h2 >> 16) | h3);
    float l0 = f.x - __uint_as_float(h0);
    float l1 = f.y - __uint_as_float(h1);
    float l2 = f.z - __uint_as_float(h2);
    float l3 = f.w - __uint_as_float(h3);
    lo = make_uint2((__float_as_uint(l0) >> 16) | (__float_as_uint(l1) & 0xFFFF0000u),
                    (__float_as_uint(l2) >> 16) | (__float_as_uint(l3) & 0xFFFF0000u));
}

__device__ __forceinline__ unsigned pack2_bf16(float a, float b) {
    __bf16 ha = (__bf16)a, hb = (__bf16)b;
    unsigned short ua = __builtin_bit_cast(unsigned short, ha);
    unsigned short ub = __builtin_bit_cast(unsigned short, hb);
    return (unsigned)ua | ((unsigned)ub << 16);
}

// ---------------------------------------------------------------------------
// Prep: transpose dw weights [C][9] -> [9][C]; fold BN into scale/shift.
// ---------------------------------------------------------------------------
__global__ void prep_kernel(
    const float* __restrict__ w1, const float* __restrict__ w2, const float* __restrict__ w3,
    const float* __restrict__ g1, const float* __restrict__ b1, const float* __restrict__ m1, const float* __restrict__ v1,
    const float* __restrict__ g2, const float* __restrict__ b2, const float* __restrict__ m2, const float* __restrict__ v2,
    const float* __restrict__ g3, const float* __restrict__ b3, const float* __restrict__ m3, const float* __restrict__ v3,
    float* __restrict__ wT1, float* __restrict__ wT2, float* __restrict__ wT3,
    float* __restrict__ sc1, float* __restrict__ sh1,
    float* __restrict__ sc2, float* __restrict__ sh2,
    float* __restrict__ sc3, float* __restrict__ sh3)
{
    int c = threadIdx.x;
#pragma unroll
    for (int t = 0; t < 9; ++t) {
        wT1[t * C_ + c] = w1[c * 9 + t];
        wT2[t * C_ + c] = w2[c * 9 + t];
        wT3[t * C_ + c] = w3[c * 9 + t];
    }
    float s1 = g1[c] * rsqrtf(v1[c] + 1e-5f); sc1[c] = s1; sh1[c] = b1[c] - m1[c] * s1;
    float s2 = g2[c] * rsqrtf(v2[c] + 1e-5f); sc2[c] = s2; sh2[c] = b2[c] - m2[c] * s2;
    float s3 = g3[c] * rsqrtf(v3[c] + 1e-5f); sc3[c] = s3; sh3[c] = b3[c] - m3[c] * s3;
}

// ---------------------------------------------------------------------------
// MFMA GEMM (NT), split-bf16, K=256, fully unrolled, 2-deep register prefetch
// (ping-pong sets; slab k+2 issued while slab k is staged -> ~1400cy distance
// > ~900cy HBM latency).
// ---------------------------------------------------------------------------
#define AHI 0
#define ALO 2560
#define BHI 5120
#define BLO 7680
__global__ __launch_bounds__(256, 2) void gemm_nt_mfma_kernel(
    const float* __restrict__ A,    // [M][256]
    const float* __restrict__ Bm,   // [N][256]
    const float* __restrict__ bias, // [N] or nullptr
    float* __restrict__ C,          // [M][N]
    int M, int N)
{
    __shared__ unsigned lds[10240];
    const int tid  = threadIdx.x;
    const int nb   = N >> 7;
    const int bx   = blockIdx.x % nb;
    const int by   = blockIdx.x / nb;
    const int lane = tid & 63;
    const int wv   = tid >> 6;
    const int wr   = wv >> 1, wc = wv & 1;
    const int l15  = lane & 15, kb = lane >> 4;

    const int srow = tid >> 1;
    const int sdw  = (tid & 1) * 8;
    const float* Ap = A  + (size_t)(by * 128 + srow) * 256 + (tid & 1) * 16;
    const float* Bp = Bm + (size_t)(bx * 128 + srow) * 256 + (tid & 1) * 16;

    f32x4 acc[4][4];
#pragma unroll
    for (int m = 0; m < 4; ++m)
#pragma unroll
        for (int n = 0; n < 4; ++n) acc[m][n] = (f32x4)(0.0f);

    float4 aP[2][4], bP[2][4];
#pragma unroll
    for (int i = 0; i < 4; ++i) {
        aP[0][i] = *(const float4*)(Ap + i * 4);
        bP[0][i] = *(const float4*)(Bp + i * 4);
    }
#pragma unroll
    for (int i = 0; i < 4; ++i) {
        aP[1][i] = *(const float4*)(Ap + 32 + i * 4);
        bP[1][i] = *(const float4*)(Bp + 32 + i * 4);
    }

#pragma unroll
    for (int k0 = 0; k0 < 256; k0 += 32) {
        const int sel = (k0 >> 5) & 1;   // const-folds after full unroll
        __syncthreads();
        {
            uint2 h[4], l[4];
#pragma unroll
            for (int i = 0; i < 4; ++i) split_bf16(aP[sel][i], h[i], l[i]);
            *(uint4*)&lds[AHI + srow * 20 + sdw]     = make_uint4(h[0].x, h[0].y, h[1].x, h[1].y);
            *(uint4*)&lds[AHI + srow * 20 + sdw + 4] = make_uint4(h[2].x, h[2].y, h[3].x, h[3].y);
            *(uint4*)&lds[ALO + srow * 20 + sdw]     = make_uint4(l[0].x, l[0].y, l[1].x, l[1].y);
            *(uint4*)&lds[ALO + srow * 20 + sdw + 4] = make_uint4(l[2].x, l[2].y, l[3].x, l[3].y);
#pragma unroll
            for (int i = 0; i < 4; ++i) split_bf16(bP[sel][i], h[i], l[i]);
            *(uint4*)&lds[BHI + srow * 20 + sdw]     = make_uint4(h[0].x, h[0].y, h[1].x, h[1].y);
            *(uint4*)&lds[BHI + srow * 20 + sdw + 4] = make_uint4(h[2].x, h[2].y, h[3].x, h[3].y);
            *(uint4*)&lds[BLO + srow * 20 + sdw]     = make_uint4(l[0].x, l[0].y, l[1].x, l[1].y);
            *(uint4*)&lds[BLO + srow * 20 + sdw + 4] = make_uint4(l[2].x, l[2].y, l[3].x, l[3].y);
        }
        if (k0 + 64 < 256) {   // prefetch slab k+2 into the set just consumed
#pragma unroll
            for (int i = 0; i < 4; ++i) aP[sel][i] = *(const float4*)(Ap + k0 + 64 + i * 4);
#pragma unroll
            for (int i = 0; i < 4; ++i) bP[sel][i] = *(const float4*)(Bp + k0 + 64 + i * 4);
        }
        __syncthreads();

        bf16x8 ah[4], al[4], bh[4], bl[4];
#pragma unroll
        for (int m = 0; m < 4; ++m) {
            int r = wr * 64 + m * 16 + l15;
            ah[m] = *(const bf16x8*)&lds[AHI + r * 20 + kb * 4];
            al[m] = *(const bf16x8*)&lds[ALO + r * 20 + kb * 4];
        }
#pragma unroll
        for (int n = 0; n < 4; ++n) {
            int r = wc * 64 + n * 16 + l15;
            bh[n] = *(const bf16x8*)&lds[BHI + r * 20 + kb * 4];
            bl[n] = *(const bf16x8*)&lds[BLO + r * 20 + kb * 4];
        }
#pragma unroll
        for (int m = 0; m < 4; ++m)
#pragma unroll
            for (int n = 0; n < 4; ++n) {
                acc[m][n] = __builtin_amdgcn_mfma_f32_16x16x32_bf16(ah[m], bh[n], acc[m][n], 0, 0, 0);
                acc[m][n] = __builtin_amdgcn_mfma_f32_16x16x32_bf16(ah[m], bl[n], acc[m][n], 0, 0, 0);
                acc[m][n] = __builtin_amdgcn_mfma_f32_16x16x32_bf16(al[m], bh[n], acc[m][n], 0, 0, 0);
            }
    }

    const int rb = by * 128 + wr * 64 + kb * 4;
    const int cb = bx * 128 + wc * 64 + l15;
#pragma unroll
    for (int n = 0; n < 4; ++n) {
        int col = cb + n * 16;
        float bv = bias ? bias[col] : 0.0f;
#pragma unroll
        for (int m = 0; m < 4; ++m) {
            int row = rb + m * 16;
#pragma unroll
            for (int r = 0; r < 4; ++r)
                C[(size_t)(row + r) * N + col] = acc[m][n][r] + bv;
        }
    }
}

// ---------------------------------------------------------------------------
// dwconv+bn+pool+gelu (unchanged from R5 — XCD-local, verified fast).
// ---------------------------------------------------------------------------
__global__ __launch_bounds__(256, 4) void dwconv_bn_pool_gelu_kernel(
    const float* __restrict__ in, const float* __restrict__ wT,
    const float* __restrict__ scv, const float* __restrict__ shv,
    float* __restrict__ outg, float* __restrict__ pool)
{
    const int blk = blockIdx.x;
    const int xcd = blk & 7;
    const int j   = blk >> 3;
    const int b   = xcd + 8 * (j >> 6);
    const int g   = j & 63;
    const int gy  = g >> 3, gx = g & 7;
    const int tid = threadIdx.x;
    const int c4  = tid & 63;
    const int wv  = tid >> 6;
    const int c0  = c4 * 4;

    float4 wr[9];
#pragma unroll
    for (int t = 0; t < 9; ++t) wr[t] = *(const float4*)(wT + t * C_ + c0);
    const float4 sc = *(const float4*)(scv + c0);
    const float4 sh = *(const float4*)(shv + c0);

    const int x0 = gx * 7, y0 = gy * 7;
    const float* inb = in + (size_t)b * N_TOK * C_;
    float4 acc = make_float4(0, 0, 0, 0);

    for (int p = wv; p < 49; p += 4) {
        int py = p / 7, px = p - py * 7;
        int y = y0 + py, x = x0 + px;
        float cx = 0.f, cy = 0.f, cz = 0.f, cw = 0.f;
#pragma unroll
        for (int dy = -1; dy <= 1; ++dy) {
            int yy = y + dy;
            if (yy < 0 || yy >= H_IMG) continue;
#pragma unroll
            for (int dx = -1; dx <= 1; ++dx) {
                int xx = x + dx;
                if (xx < 0 || xx >= W_IMG) continue;
                const float4 iv = *(const float4*)(inb + (size_t)(yy * W_IMG + xx) * C_ + c0);
                const float4 w  = wr[(dy + 1) * 3 + (dx + 1)];
                cx = fmaf(iv.x, w.x, cx);
                cy = fmaf(iv.y, w.y, cy);
                cz = fmaf(iv.z, w.z, cz);
                cw = fmaf(iv.w, w.w, cw);
            }
        }
        float vx = cx * sc.x + sh.x;
        float vy = cy * sc.y + sh.y;
        float vz = cz * sc.z + sh.z;
        float vw = cw * sc.w + sh.w;
        acc.x += vx; acc.y += vy; acc.z += vz; acc.w += vw;
        *(float4*)(outg + ((size_t)b * N_TOK + y * W_IMG + x) * C_ + c0) =
            make_float4(geluf(vx), geluf(vy), geluf(vz), geluf(vw));
    }

    __shared__ float4 ps[4][64];
    ps[wv][c4] = acc;
    __syncthreads();
    if (tid < 64) {
        float4 s  = ps[0][tid];
        float4 t1 = ps[1][tid];
        float4 t2 = ps[2][tid];
        float4 t3 = ps[3][tid];
        const float r = 1.0f / 49.0f;
        *(float4*)(pool + ((size_t)b * 64 + g) * C_ + tid * 4) = make_float4(
            (s.x + t1.x + t2.x + t3.x) * r, (s.y + t1.y + t2.y + t3.y) * r,
            (s.z + t1.z + t2.z + t3.z) * r, (s.w + t1.w + t2.w + t3.w) * r);
    }
}

// ---------------------------------------------------------------------------
// FUSED conv3x3(bilinear_up(o_small)) + BN + add, column-march version.
// A block's 9x9 fine halo maps to a 3x3 coarse patch (rows gy-1..gy+1,
// cols gx-1..gx+1 clamped). Per thread-column: x-lerp the patch once into
// CX[3][3], then march y with a 3-row ring — each pixel costs 3 float4
// y-lerps (uniform scalar coefficients) + 36 conv FMA. Threads: c4 = tid&63
// (channel quad), wv = column owner (cols wv, wv+4).
// ---------------------------------------------------------------------------
__global__ __launch_bounds__(256, 3) void dwconv_up_bn_add_kernel(
    const float* __restrict__ osm,    // [B][8][8][C]
    const float* __restrict__ wT,     // [9][C]
    const float* __restrict__ scv, const float* __restrict__ shv,
    const float* __restrict__ add_,   // [B][56][56][C]
    float* __restrict__ out)
{
    const int blk = blockIdx.x;
    const int xcd = blk & 7;
    const int j   = blk >> 3;
    const int b   = xcd + 8 * (j >> 6);
    const int g   = j & 63;
    const int gy  = g >> 3, gx = g & 7;
    const int tid = threadIdx.x;
    const int c4  = tid & 63;
    const int wv  = tid >> 6;
    const int c0  = c4 * 4;

    float4 wr[9];
#pragma unroll
    for (int t = 0; t < 9; ++t) wr[t] = *(const float4*)(wT + t * C_ + c0);
    const float4 sc = *(const float4*)(scv + c0);
    const float4 sh = *(const float4*)(shv + c0);

    const float* ob = osm + (size_t)b * 64 * C_ + c0;
    const int cry0 = max(gy - 1, 0), cry1 = gy, cry2 = min(gy + 1, 7);
    const int crx0 = max(gx - 1, 0), crx1 = gx, crx2 = min(gx + 1, 7);

    for (int cpass = 0; cpass < 2; ++cpass) {
        const int xi = wv + cpass * 4;
        if (xi >= 7) break;                       // wave-uniform
        const int x = gx * 7 + xi;

        // conv-col x-lerp coefficients (wave-uniform)
        float xt[3]; int rixv[3]; bool xval[3];
#pragma unroll
        for (int e = 0; e < 3; ++e) {
            int xx = x - 1 + e;
            xval[e] = (xx >= 0 && xx < W_IMG);
            if (xval[e]) {
                int i0, i1; float t;
                up_coef(xx, i0, i1, t);
                rixv[e] = i0 - gx + 1;            // 0 or 1
                xt[e]   = t;
            } else { rixv[e] = 0; xt[e] = 0.f; }
        }

        // CX[ri][e]: x-lerped coarse value at patch row ri, conv col e
        float4 CX[3][3];
#pragma unroll
        for (int ri = 0; ri < 3; ++ri) {
            const int rowc = (ri == 0) ? cry0 : ((ri == 1) ? cry1 : cry2);
            const float4 p0 = *(const float4*)(ob + (size_t)(rowc * 8 + crx0) * C_);
            const float4 p1 = *(const float4*)(ob + (size_t)(rowc * 8 + crx1) * C_);
            const float4 p2 = *(const float4*)(ob + (size_t)(rowc * 8 + crx2) * C_);
#pragma unroll
            for (int e = 0; e < 3; ++e) {
                const bool h2 = rixv[e] != 0;
                float lox = h2 ? p1.x : p0.x, hix = h2 ? p2.x : p1.x;
                float loy = h2 ? p1.y : p0.y, hiy = h2 ? p2.y : p1.y;
                float loz = h2 ? p1.z : p0.z, hiz = h2 ? p2.z : p1.z;
                float low = h2 ? p1.w : p0.w, hiw = h2 ? p2.w : p1.w;
                const float t = xt[e];
                float vx = fmaf(t, hix - lox, lox);
                float vy = fmaf(t, hiy - loy, loy);
                float vz = fmaf(t, hiz - loz, loz);
                float vw = fmaf(t, hiw - low, low);
                if (!xval[e]) { vx = vy = vz = vw = 0.f; }
                CX[ri][e] = make_float4(vx, vy, vz, vw);
            }
        }

        // y-lerp one upsampled row (coefficients block-uniform -> scalar)
#define UPROW(YY, U)                                                          \
        {                                                                     \
            int i0_, i1_; float t_;                                           \
            up_coef((YY), i0_, i1_, t_);                                      \
            const bool h2_ = (i0_ - gy + 1) != 0;                             \
            _Pragma("unroll")                                                 \
            for (int e = 0; e < 3; ++e) {                                     \
                const float4 lo = h2_ ? CX[1][e] : CX[0][e];                  \
                const float4 hi = h2_ ? CX[2][e] : CX[1][e];                  \
                U[e] = make_float4(fmaf(t_, hi.x - lo.x, lo.x),               \
                                   fmaf(t_, hi.y - lo.y, lo.y),               \
                                   fmaf(t_, hi.z - lo.z, lo.z),               \
                                   fmaf(t_, hi.w - lo.w, lo.w));              \
            }                                                                 \
        }

        float4 Um[3], U0[3], Up[3];
        UPROW(gy * 7 - 1, Um);
        UPROW(gy * 7,     U0);
#pragma unroll
        for (int y7 = 0; y7 < 7; ++y7) {
            const int y = gy * 7 + y7;
            UPROW(y + 1, Up);
            float ax = 0.f, ay = 0.f, az = 0.f, aw = 0.f;
            if (!(gy == 0 && y7 == 0)) {
#pragma unroll
                for (int e = 0; e < 3; ++e) {
                    const float4 w = wr[e];
                    ax = fmaf(Um[e].x, w.x, ax); ay = fmaf(Um[e].y, w.y, ay);
                    az = fmaf(Um[e].z, w.z, az); aw = fmaf(Um[e].w, w.w, aw);
                }
            }
#pragma unroll
            for (int e = 0; e < 3; ++e) {
                const float4 w = wr[3 + e];
                ax = fmaf(U0[e].x, w.x, ax); ay = fmaf(U0[e].y, w.y, ay);
                az = fmaf(U0[e].z, w.z, az); aw = fmaf(U0[e].w, w.w, aw);
            }
            if (!(gy == 7 && y7 == 6)) {
#pragma unroll
                for (int e = 0; e < 3; ++e) {
                    const float4 w = wr[6 + e];
                    ax = fmaf(Up[e].x, w.x, ax); ay = fmaf(Up[e].y, w.y, ay);
                    az = fmaf(Up[e].z, w.z, az); aw = fmaf(Up[e].w, w.w, aw);
                }
            }
            const size_t pix = (size_t)b * N_TOK + (size_t)y * W_IMG + x;
            const float4 av = *(const float4*)(add_ + pix * C_ + c0);
            *(float4*)(out + pix * C_ + c0) = make_float4(
                ax * sc.x + sh.x + av.x, ay * sc.y + sh.y + av.y,
                az * sc.z + sh.z + av.z, aw * sc.w + sh.w + av.w);
#pragma unroll
            for (int e = 0; e < 3; ++e) { Um[e] = U0[e]; U0[e] = Up[e]; }
        }
#undef UPROW
    }
}

// ---------------------------------------------------------------------------
// QK^T logits + per-row max (scaled).
// ---------------------------------------------------------------------------
__global__ __launch_bounds__(256) void qk_kernel(
    const float* __restrict__ q, const float* __restrict__ k,
    float* __restrict__ attnL, float* __restrict__ mrow_g)
{
    int bh = blockIdx.x;
    int b = bh >> 3, head = bh & 7;
    __shared__ float qs[64][33];
    __shared__ float ks[64][33];
    int tid = threadIdx.x;
    for (int t = tid; t < 512; t += 256) {
        int i = t >> 3, dq = (t & 7) * 4;
        const float4 qv = *(const float4*)(q + ((size_t)(b * 64 + i) * C_ + head * 32 + dq));
        const float4 kv = *(const float4*)(k + ((size_t)(b * 64 + i) * C_ + head * 32 + dq));
        qs[i][dq + 0] = qv.x; qs[i][dq + 1] = qv.y; qs[i][dq + 2] = qv.z; qs[i][dq + 3] = qv.w;
        ks[i][dq + 0] = kv.x; ks[i][dq + 1] = kv.y; ks[i][dq + 2] = kv.z; ks[i][dq + 3] = kv.w;
    }
    __syncthreads();
    int i  = tid >> 2;
    int jb = (tid & 3) * 16;
    float qr[32];
#pragma unroll
    for (int d = 0; d < 32; ++d) qr[d] = qs[i][d];
    float* outp = attnL + (size_t)bh * 4096 + i * 64 + jb;
    float mloc = -1e30f;
#pragma unroll
    for (int j = 0; j < 16; ++j) {
        float s = 0.f;
#pragma unroll
        for (int d = 0; d < 32; ++d) s = fmaf(qr[d], ks[jb + j][d], s);
        float sv = s * 0.0625f;          // C^-0.5
        outp[j] = sv;
        mloc = fmaxf(mloc, sv);
    }
    mloc = fmaxf(mloc, __shfl_xor(mloc, 1));
    mloc = fmaxf(mloc, __shfl_xor(mloc, 2));
    if ((tid & 3) == 0) mrow_g[bh * 64 + i] = mloc;
}

// ---------------------------------------------------------------------------
// Fused upsample(logits)->softmax-weights->PV via MFMA (unchanged from R6).
// ---------------------------------------------------------------------------
#define S_ALS 0
#define S_P   1792
#define S_VH  4096
#define S_VL  5248
#define S_RY  6400
#define S_ZP  7168
__global__ __launch_bounds__(256, 4) void attn_pv_kernel(
    const float* __restrict__ attnL,
    const float* __restrict__ mrow_g,
    const float* __restrict__ v,
    float* __restrict__ part_o,
    float* __restrict__ part_z)
{
    __shared__ unsigned sm[7424];
    float* smf = (float*)sm;

    const int blk   = blockIdx.x;
    const int xcd   = blk & 7;
    const int r8    = blk >> 3;
    const int b     = xcd + 8 * (r8 >> 6);
    const int rem   = r8 & 63;
    const int head  = rem >> 3;
    const int chunk = rem & 7;
    const int bh    = b * 8 + head;
    const int jb    = min(max(chunk - 1, 0), 5);

    const int tid  = threadIdx.x;
    const int lane = tid & 63;
    const int w    = tid >> 6;
    const int l15  = lane & 15, kb = lane >> 4;
    const int i    = tid >> 2;
    const int dg   = tid & 3;

    for (int u = tid; u < 384; u += 256) {
        int row = u / 6, cc = u % 6;
        float4 va = *(const float4*)(attnL + (size_t)bh * 4096 + row * 64 + jb * 8 + cc * 4);
        *(float4*)&smf[S_ALS + row * 28 + cc * 4] = va;
    }
    sm[S_P + (tid >> 2) * 36 + 28 + (tid & 3)] = 0;
    {
        int base = (tid < 128) ? S_VH : S_VL;
        int q2 = tid & 127;
        sm[base + (q2 >> 2) * 36 + 28 + (q2 & 3)] = 0;
    }
    const float mr = mrow_g[bh * 64 + i];

    int   x0a[14]; float txa[14];
#pragma unroll
    for (int j = 0; j < 14; ++j) {
        int i0, i1; float t;
        up_coef(dg * 14 + j, i0, i1, t);
        x0a[j] = i0; txa[j] = t;
    }

    f32x4 acc[2];
    acc[0] = (f32x4)(0.0f); acc[1] = (f32x4)(0.0f);
    float zacc = 0.0f;

    for (int rr = 0; rr < 7; ++rr) {
        const int y = chunk * 7 + rr;
        __syncthreads();

        float4 va, vb;
        if (tid < 224) {
            int x2 = tid >> 3, d0 = (tid & 7) * 4;
            const float* vp = v + ((size_t)b * N_TOK + y * W_IMG + 2 * x2) * C_ + head * 32 + d0;
            va = *(const float4*)vp;
            vb = *(const float4*)(vp + C_);
        }
        {
            int y0, y1; float ty;
            up_coef(y, y0, y1, ty);
#pragma unroll
            for (int kk2 = dg; kk2 < 9; kk2 += 4) {
                int ks2 = kk2 < 8 ? kk2 : 7;
                float a0 = smf[S_ALS + i * 28 + (y0 - jb) * 8 + ks2];
                float a1 = smf[S_ALS + i * 28 + (y1 - jb) * 8 + ks2];
                smf[S_RY + i * 12 + kk2] = fmaf(ty, a1 - a0, a0) - mr;
            }
        }
        if (tid < 224) {
            int x2 = tid >> 3, d0 = (tid & 7) * 4;
            float ae[4] = {va.x, va.y, va.z, va.w};
            float be[4] = {vb.x, vb.y, vb.z, vb.w};
#pragma unroll
            for (int j = 0; j < 4; ++j) {
                unsigned ua = __float_as_uint(ae[j]), ha = ua & 0xFFFF0000u;
                unsigned ub = __float_as_uint(be[j]), hb2 = ub & 0xFFFF0000u;
                sm[S_VH + (d0 + j) * 36 + x2] = (ha >> 16) | hb2;
                float la = ae[j] - __uint_as_float(ha);
                float lb = be[j] - __uint_as_float(hb2);
                sm[S_VL + (d0 + j) * 36 + x2] =
                    (__float_as_uint(la) >> 16) | (__float_as_uint(lb) & 0xFFFF0000u);
            }
        }
        __syncthreads();

#pragma unroll
        for (int j = 0; j < 7; ++j) {
            float r0 = smf[S_RY + i * 12 + x0a[2 * j]];
            float r1 = smf[S_RY + i * 12 + x0a[2 * j] + 1];
            float l0 = fmaf(txa[2 * j], r1 - r0, r0);
            float r2 = smf[S_RY + i * 12 + x0a[2 * j + 1]];
            float r3 = smf[S_RY + i * 12 + x0a[2 * j + 1] + 1];
            float l1 = fmaf(txa[2 * j + 1], r3 - r2, r2);
            float p0 = __expf(l0), p1 = __expf(l1);
            zacc += p0 + p1;
            sm[S_P + i * 36 + dg * 7 + j] = pack2_bf16(p0, p1);
        }
        __syncthreads();

#pragma unroll
        for (int s = 0; s < 2; ++s) {
            bf16x8 pa = *(const bf16x8*)&sm[S_P + (w * 16 + l15) * 36 + s * 16 + kb * 4];
#pragma unroll
            for (int n = 0; n < 2; ++n) {
                bf16x8 bhv = *(const bf16x8*)&sm[S_VH + (n * 16 + l15) * 36 + s * 16 + kb * 4];
                bf16x8 blv = *(const bf16x8*)&sm[S_VL + (n * 16 + l15) * 36 + s * 16 + kb * 4];
                acc[n] = __builtin_amdgcn_mfma_f32_16x16x32_bf16(pa, bhv, acc[n], 0, 0, 0);
                acc[n] = __builtin_amdgcn_mfma_f32_16x16x32_bf16(pa, blv, acc[n], 0, 0, 0);
            }
        }
    }

    smf[S_ZP + i * 4 + dg] = zacc;
    __syncthreads();
    if (tid < 64) {
        float zt = smf[S_ZP + tid * 4] + smf[S_ZP + tid * 4 + 1] +
                   smf[S_ZP + tid * 4 + 2] + smf[S_ZP + tid * 4 + 3];
        part_z[((size_t)bh * NCH + chunk) * 64 + tid] = zt;
    }
    const int row4 = (lane >> 4) * 4;
#pragma unroll
    for (int n = 0; n < 2; ++n)
#pragma unroll
        for (int r2 = 0; r2 < 4; ++r2) {
            int i2 = w * 16 + row4 + r2;
            int d  = n * 16 + l15;
            part_o[(((size_t)bh * NCH + chunk) * 64 + i2) * 32 + d] = acc[n][r2];
        }
}

// ---------------------------------------------------------------------------
// Combine partials -> o_small [B][64][C], divide by Z.
// ---------------------------------------------------------------------------
__global__ __launch_bounds__(256) void combine_kernel(
    const float* __restrict__ part_o, const float* __restrict__ part_z,
    float* __restrict__ o_small)
{
    int idx = blockIdx.x * 256 + threadIdx.x;
    if (idx >= B_ * 64 * C_) return;
    int c = idx % C_;
    int g = (idx / C_) % 64;
    int b = idx / (C_ * 64);
    int head = c >> 5, d = c & 31;
    int bh = b * 8 + head;
    float oo = 0.f, zz = 0.f;
    for (int ch = 0; ch < NCH; ++ch) {
        oo += part_o[(((size_t)bh * NCH + ch) * 64 + g) * 32 + d];
        zz += part_z[((size_t)bh * NCH + ch) * 64 + g];
    }
    o_small[idx] = oo / zz;
}

// ---------------------------------------------------------------------------
extern "C" void kernel_launch(void* const* d_in, const int* in_sizes, int n_in,
                              void* d_out, int out_size, void* d_ws, size_t ws_size,
                              hipStream_t stream)
{
    const float* x    = (const float*)d_in[0];
    const float* Wv   = (const float*)d_in[1];
    const float* c1w  = (const float*)d_in[2];
    const float* b1g  = (const float*)d_in[3];
    const float* b1b  = (const float*)d_in[4];
    const float* b1m  = (const float*)d_in[5];
    const float* b1v  = (const float*)d_in[6];
    const float* c2w  = (const float*)d_in[7];
    const float* b2g  = (const float*)d_in[8];
    const float* b2b  = (const float*)d_in[9];
    const float* b2m  = (const float*)d_in[10];
    const float* b2v  = (const float*)d_in[11];
    const float* vupw = (const float*)d_in[12];
    const float* b3g  = (const float*)d_in[13];
    const float* b3b  = (const float*)d_in[14];
    const float* b3m  = (const float*)d_in[15];
    const float* b3v  = (const float*)d_in[16];
    const float* Wp   = (const float*)d_in[17];
    const float* bp   = (const float*)d_in[18];
    float* out = (float*)d_out;
    float* ws  = (float*)d_ws;

    const size_t SZ = (size_t)B_ * N_TOK * C_;
    float* v       = ws;
    float* s1g     = v   + SZ;
    float* s2g     = s1g + SZ;
    float* q       = s2g + SZ;
    float* kk      = q  + (size_t)B_ * 64 * C_;
    float* attnL   = kk + (size_t)B_ * 64 * C_;
    float* part_o  = attnL  + (size_t)B_ * 8 * 64 * 64;
    float* part_z  = part_o + (size_t)B_ * 8 * NCH * 64 * 32;
    float* o_small = part_z + (size_t)B_ * 8 * NCH * 64;
    float* wT1     = o_small + (size_t)B_ * 64 * C_;
    float* wT2     = wT1 + 9 * C_;
    float* wT3     = wT2 + 9 * C_;
    float* sc1     = wT3 + 9 * C_;
    float* sh1     = sc1 + C_;
    float* sc2     = sh1 + C_;
    float* sh2     = sc2 + C_;
    float* sc3     = sh2 + C_;
    float* sh3     = sc3 + C_;
    float* mrow_g  = sh3 + C_;

    const int M = B_ * N_TOK;

    prep_kernel<<<1, 256, 0, stream>>>(c1w, c2w, vupw,
        b1g, b1b, b1m, b1v, b2g, b2b, b2m, b2v, b3g, b3b, b3m, b3v,
        wT1, wT2, wT3, sc1, sh1, sc2, sh2, sc3, sh3);
    gemm_nt_mfma_kernel<<<(M / 128) * (C_ / 128), 256, 0, stream>>>(x, Wv, nullptr, v, M, C_);
    dwconv_bn_pool_gelu_kernel<<<1024, 256, 0, stream>>>(v, wT1, sc1, sh1, s1g, q);
    dwconv_bn_pool_gelu_kernel<<<1024, 256, 0, stream>>>(s1g, wT2, sc2, sh2, s2g, kk);
    qk_kernel<<<B_ * 8, 256, 0, stream>>>(q, kk, attnL, mrow_g);
    attn_pv_kernel<<<B_ * 8 * NCH, 256, 0, stream>>>(attnL, mrow_g, v, part_o, part_z);
    combine_kernel<<<B_ * 64 * C_ / 256, 256, 0, stream>>>(part_o, part_z, o_small);
    dwconv_up_bn_add_kernel<<<1024, 256, 0, stream>>>(o_small, wT3, sc3, sh3, s2g, v);
    gemm_nt_mfma_kernel<<<(M / 128) * (C_ / 128), 256, 0, stream>>>(v, Wp, bp, out, M, C_);
}